// Round 5
// baseline (3644.655 us; speedup 1.0000x reference)
//
#include <hip/hip_runtime.h>

typedef __bf16 bf16x8 __attribute__((ext_vector_type(8)));
typedef float f32x4 __attribute__((ext_vector_type(4)));
typedef unsigned short ushort_t;
typedef unsigned short u16x8 __attribute__((ext_vector_type(8)));

#define BSZ 4096
#define HID 1024
#define INPD 512
#define NSPAN 8
#define NOUT 2
#define NDAYS 20
#define XLD 1536  // X = [inp(512) | h(1024)] leading dim

__device__ __forceinline__ ushort_t f2bf(float f) {
  union { float f; unsigned u; } v; v.f = f;
  unsigned r = v.u + 0x7FFFu + ((v.u >> 16) & 1u);
  return (ushort_t)(r >> 16);
}
__device__ __forceinline__ float bf2f(ushort_t b) {
  union { unsigned u; float f; } v; v.u = ((unsigned)b) << 16;
  return v.f;
}
__device__ __forceinline__ float sigf(float x) { return 1.f / (1.f + __expf(-x)); }
__device__ __forceinline__ float tanhfast(float x) { return 2.f / (1.f + __expf(-2.f * x)) - 1.f; }

__device__ __forceinline__ void gload16(const void* g, void* l) {
  __builtin_amdgcn_global_load_lds((const __attribute__((address_space(1))) void*)g,
                                   (__attribute__((address_space(3))) void*)l, 16, 0, 0);
}

// ---------------------------------------------------------------------------
// Weight prep: Wg[r][c] bf16, r = (j/16)*64 + gate*16 + (j%16), c = [W_ih | W_hh]
// ---------------------------------------------------------------------------
__global__ void prep_gates_w(const float* __restrict__ Wih, const float* __restrict__ Whh,
                             const float* __restrict__ bih, const float* __restrict__ bhh,
                             ushort_t* __restrict__ Wg, float* __restrict__ bg) {
  int gid = blockIdx.x * 256 + threadIdx.x;  // over 4096*1536
  int r = gid / XLD;
  int cc = gid - r * XLD;
  int g = (r >> 4) & 3;
  int j = (r >> 6) * 16 + (r & 15);
  int src = g * HID + j;
  float v = (cc < INPD) ? Wih[(size_t)src * INPD + cc] : Whh[(size_t)src * HID + (cc - INPD)];
  Wg[gid] = f2bf(v);
  if (cc == 0) bg[r] = bih[src] + bhh[src];
}

__global__ void prep_fcin_w(const float* __restrict__ W, ushort_t* __restrict__ Wo) {
  int gid = blockIdx.x * 256 + threadIdx.x;  // over 512*1024
  Wo[gid] = f2bf(W[gid]);
}

// X_A = [0 | bf16(hx)], c = cx
__global__ void init_kernel(const float* __restrict__ hx, const float* __restrict__ cx,
                            ushort_t* __restrict__ X, float* __restrict__ c) {
  int gid = blockIdx.x * 256 + threadIdx.x;  // over 4096*1024
  int b = gid >> 10, j = gid & 1023;
  X[(size_t)b * XLD + INPD + j] = f2bf(hx[gid]);
  if (j < INPD) X[(size_t)b * XLD + j] = 0;
  c[gid] = cx[gid];
}

// num_spans = softmax(hx @ W_span.T + b_span), fp32
__global__ void span_kernel(const float* __restrict__ hx, const float* __restrict__ Wspan,
                            const float* __restrict__ bspan, float* __restrict__ out) {
  int gid = blockIdx.x * 256 + threadIdx.x;  // over 4096*8
  int b = gid >> 3, o = gid & 7;
  const float4* hr = (const float4*)(hx + (size_t)b * HID);
  const float4* wr = (const float4*)(Wspan + (size_t)o * HID);
  float acc = 0.f;
  for (int i = 0; i < HID / 4; ++i) {
    float4 h = hr[i], w = wr[i];
    acc += h.x * w.x + h.y * w.y + h.z * w.z + h.w * w.w;
  }
  acc += bspan[o];
  float m = acc;
  for (int s = 1; s < 8; s <<= 1) m = fmaxf(m, __shfl_xor(m, s));
  float e = __expf(acc - m);
  float ssum = e;
  for (int s = 1; s < 8; s <<= 1) ssum += __shfl_xor(ssum, s);
  out[gid] = e / ssum;
}

// standalone fcout (used only for t = NDAYS-1)
__global__ void fcout_kernel(const ushort_t* __restrict__ X, const float* __restrict__ W,
                             const float* __restrict__ bvec, float* __restrict__ outp, int t) {
  const int lane = threadIdx.x & 63;
  const int wave = threadIdx.x >> 6;
  const int b = blockIdx.x * 4 + wave;
  const ushort_t* h = X + (size_t)b * XLD + INPD + lane * 16;
  u16x8 h0 = *(const u16x8*)(h);
  u16x8 h1 = *(const u16x8*)(h + 8);
  const float* w0 = W + lane * 16;
  const float* w1 = W + HID + lane * 16;
  float l0 = 0.f, l1 = 0.f;
#pragma unroll
  for (int j = 0; j < 8; ++j) {
    float ha = bf2f(h0[j]);
    l0 += ha * w0[j];
    l1 += ha * w1[j];
    float hb = bf2f(h1[j]);
    l0 += hb * w0[j + 8];
    l1 += hb * w1[j + 8];
  }
#pragma unroll
  for (int s = 32; s > 0; s >>= 1) {
    l0 += __shfl_xor(l0, s);
    l1 += __shfl_xor(l1, s);
  }
  if (lane == 0) {
    l0 += bvec[0];
    l1 += bvec[1];
    float m = fmaxf(l0, l1);
    float e0 = __expf(l0 - m), e1 = __expf(l1 - m);
    float inv = 1.f / (e0 + e1);
    float* o = outp + (size_t)b * (NDAYS * NOUT) + t * NOUT;
    o[0] = e0 * inv;
    o[1] = e1 * inv;
  }
}

// ---------------------------------------------------------------------------
// Gates GEMM: R2's m97-style 128x128/BK=32/4-wave structure + FRAG-LINEAR LDS
// (0 bank conflicts: LDS holds 16x16x32 MFMA frags contiguously; the global
// source address per lane implements the permutation, gload dest stays linear
// per rule #21). Fused LSTM cell epilogue.
// Frag f (0..7 per operand): rows f*16..+16 of the 128-tile, k 0..32.
// Lane li of frag: row f*16+(li&15), k=(li>>4)*8..+8  -> exactly the MFMA
// A/B operand mapping, so a wave's frag read is one contiguous 1KB ds_read.
// ---------------------------------------------------------------------------
__global__ void gates128_kernel(const ushort_t* __restrict__ A,
                                const ushort_t* __restrict__ B,
                                const float* __restrict__ bias, float* __restrict__ cbuf,
                                ushort_t* __restrict__ hout) {
  __shared__ __align__(16) ushort_t ldsA[128 * 32];
  __shared__ __align__(16) ushort_t ldsB[128 * 32];
  const int tid = threadIdx.x;
  const int lane = tid & 63;
  const int wave = tid >> 6;

  // XCD-aware bijective swizzle (nwg = 1024, %8==0)
  int bid = blockIdx.y * gridDim.x + blockIdx.x;
  int nwg = gridDim.x * gridDim.y;
  int cpx = nwg >> 3;
  int swz = (bid & 7) * cpx + (bid >> 3);
  int bx = swz % gridDim.x;
  int by = swz / gridDim.x;
  const int bm = bx * 128;
  const int bn = by * 128;
  const int wm = (wave >> 1) * 64;
  const int wn = (wave & 1) * 64;

  f32x4 acc[4][4] = {};

  // staging: wave w stages frags {2w, 2w+1} of A and of B (4 gloads/iter)
  const int f0 = wave * 2, f1 = wave * 2 + 1;
  const ushort_t* gA0 = A + (size_t)(bm + f0 * 16 + (lane & 15)) * XLD + ((lane >> 4) << 3);
  const ushort_t* gA1 = A + (size_t)(bm + f1 * 16 + (lane & 15)) * XLD + ((lane >> 4) << 3);
  const ushort_t* gB0 = B + (size_t)(bn + f0 * 16 + (lane & 15)) * XLD + ((lane >> 4) << 3);
  const ushort_t* gB1 = B + (size_t)(bn + f1 * 16 + (lane & 15)) * XLD + ((lane >> 4) << 3);

  for (int k0 = 0; k0 < XLD; k0 += 32) {
    gload16(gA0 + k0, ldsA + f0 * 512);
    gload16(gA1 + k0, ldsA + f1 * 512);
    gload16(gB0 + k0, ldsB + f0 * 512);
    gload16(gB1 + k0, ldsB + f1 * 512);
    __syncthreads();

    bf16x8 af[4], bf[4];
#pragma unroll
    for (int i = 0; i < 4; ++i) {
      af[i] = *(const bf16x8*)(ldsA + ((wm >> 4) + i) * 512 + lane * 8);
      bf[i] = *(const bf16x8*)(ldsB + ((wn >> 4) + i) * 512 + lane * 8);
    }
#pragma unroll
    for (int mi = 0; mi < 4; ++mi)
#pragma unroll
      for (int ni = 0; ni < 4; ++ni)
        acc[mi][ni] = __builtin_amdgcn_mfma_f32_16x16x32_bf16(af[mi], bf[ni], acc[mi][ni], 0, 0, 0);
    __syncthreads();
  }

  // fused LSTM epilogue: 64-col group = gates i,f,g,o for 16 hidden units
  const int colbase = bn + wn;  // multiple of 64
  const int jj = (colbase >> 6) * 16 + (lane & 15);
  const int cb = colbase + (lane & 15);
  const float bI = bias[cb];
  const float bF = bias[cb + 16];
  const float bG = bias[cb + 32];
  const float bO = bias[cb + 48];
#pragma unroll
  for (int mi = 0; mi < 4; ++mi) {
#pragma unroll
    for (int r = 0; r < 4; ++r) {
      const int b = bm + wm + mi * 16 + ((lane >> 4) << 2) + r;
      float ig = sigf(acc[mi][0][r] + bI);
      float fg = sigf(acc[mi][1][r] + bF);
      float gg = tanhfast(acc[mi][2][r] + bG);
      float og = sigf(acc[mi][3][r] + bO);
      size_t cidx = (size_t)b * HID + jj;
      float cn = fg * cbuf[cidx] + ig * gg;
      cbuf[cidx] = cn;
      hout[(size_t)b * XLD + INPD + jj] = f2bf(og * tanhfast(cn));
    }
  }
}

// ---------------------------------------------------------------------------
// fcin GEMM (same frag-linear 128x128 structure, K=1024) with FUSED fcout:
// by==0 blocks stream the full h-panel of their 128 rows through ldsA, so they
// also accumulate the 2 fcout logits per row (thread tid -> row tid/2, k-half
// tid&1) and write softmax'd outputs for step t.
// ---------------------------------------------------------------------------
__global__ void fcin128_kernel(const ushort_t* __restrict__ A,
                               const ushort_t* __restrict__ B,
                               const float* __restrict__ bias, ushort_t* __restrict__ hout,
                               const float* __restrict__ Wout, const float* __restrict__ bout,
                               float* __restrict__ outp, int t) {
  __shared__ __align__(16) ushort_t ldsA[128 * 32];
  __shared__ __align__(16) ushort_t ldsB[128 * 32];
  const int tid = threadIdx.x;
  const int lane = tid & 63;
  const int wave = tid >> 6;

  int bid = blockIdx.y * gridDim.x + blockIdx.x;  // nwg = 128, %8==0
  int nwg = gridDim.x * gridDim.y;
  int cpx = nwg >> 3;
  int swz = (bid & 7) * cpx + (bid >> 3);
  int bx = swz % gridDim.x;
  int by = swz / gridDim.x;
  const int bm = bx * 128;
  const int bn = by * 128;
  const int wm = (wave >> 1) * 64;
  const int wn = (wave & 1) * 64;
  const bool doOut = (by == 0);

  f32x4 acc[4][4] = {};
  float lo0 = 0.f, lo1 = 0.f;
  const int orow = tid >> 1, okh = tid & 1;
  const int ofr = orow >> 4, orw = orow & 15;

  const int f0 = wave * 2, f1 = wave * 2 + 1;
  const ushort_t* gA0 = A + (size_t)(bm + f0 * 16 + (lane & 15)) * XLD + ((lane >> 4) << 3);
  const ushort_t* gA1 = A + (size_t)(bm + f1 * 16 + (lane & 15)) * XLD + ((lane >> 4) << 3);
  const ushort_t* gB0 = B + (size_t)(bn + f0 * 16 + (lane & 15)) * HID + ((lane >> 4) << 3);
  const ushort_t* gB1 = B + (size_t)(bn + f1 * 16 + (lane & 15)) * HID + ((lane >> 4) << 3);

  for (int k0 = 0; k0 < HID; k0 += 32) {
    gload16(gA0 + k0, ldsA + f0 * 512);
    gload16(gA1 + k0, ldsA + f1 * 512);
    gload16(gB0 + k0, ldsB + f0 * 512);
    gload16(gB1 + k0, ldsB + f1 * 512);
    __syncthreads();

    bf16x8 af[4], bf[4];
#pragma unroll
    for (int i = 0; i < 4; ++i) {
      af[i] = *(const bf16x8*)(ldsA + ((wm >> 4) + i) * 512 + lane * 8);
      bf[i] = *(const bf16x8*)(ldsB + ((wn >> 4) + i) * 512 + lane * 8);
    }
#pragma unroll
    for (int mi = 0; mi < 4; ++mi)
#pragma unroll
      for (int ni = 0; ni < 4; ++ni)
        acc[mi][ni] = __builtin_amdgcn_mfma_f32_16x16x32_bf16(af[mi], bf[ni], acc[mi][ni], 0, 0, 0);

    if (doOut) {
      // row orow, k in [k0 + okh*16, +16): two contiguous 8-elem LDS reads
      u16x8 h0 = *(const u16x8*)(ldsA + ofr * 512 + ((okh * 32) + orw) * 8);
      u16x8 h1 = *(const u16x8*)(ldsA + ofr * 512 + ((okh * 32 + 16) + orw) * 8);
      const float* w0 = Wout + k0 + okh * 16;
      const float* w1 = Wout + HID + k0 + okh * 16;
#pragma unroll
      for (int j = 0; j < 8; ++j) {
        float ha = bf2f(h0[j]), hb = bf2f(h1[j]);
        lo0 += ha * w0[j] + hb * w0[j + 8];
        lo1 += ha * w1[j] + hb * w1[j + 8];
      }
    }
    __syncthreads();
  }

#pragma unroll
  for (int mi = 0; mi < 4; ++mi) {
#pragma unroll
    for (int ni = 0; ni < 4; ++ni) {
      const int n = bn + wn + ni * 16 + (lane & 15);
      const float bb = bias[n];
#pragma unroll
      for (int r = 0; r < 4; ++r) {
        const int b = bm + wm + mi * 16 + ((lane >> 4) << 2) + r;
        float v = fmaxf(acc[mi][ni][r] + bb, 0.f);
        hout[(size_t)b * XLD + n] = f2bf(v);
      }
    }
  }

  if (doOut) {
    lo0 += __shfl_xor(lo0, 1);
    lo1 += __shfl_xor(lo1, 1);
    if (okh == 0) {
      float l0 = lo0 + bout[0];
      float l1 = lo1 + bout[1];
      float m = fmaxf(l0, l1);
      float e0 = __expf(l0 - m), e1 = __expf(l1 - m);
      float inv = 1.f / (e0 + e1);
      float* o = outp + (size_t)(bm + orow) * (NDAYS * NOUT) + t * NOUT;
      o[0] = e0 * inv;
      o[1] = e1 * inv;
    }
  }
}

extern "C" void kernel_launch(void* const* d_in, const int* in_sizes, int n_in, void* d_out,
                              int out_size, void* d_ws, size_t ws_size, hipStream_t stream) {
  const float* hx = (const float*)d_in[0];
  const float* cx = (const float*)d_in[1];
  const float* Wih = (const float*)d_in[2];
  const float* Whh = (const float*)d_in[3];
  const float* bih = (const float*)d_in[4];
  const float* bhh = (const float*)d_in[5];
  const float* Wfcin = (const float*)d_in[6];
  const float* bfcin = (const float*)d_in[7];
  const float* Wfcout = (const float*)d_in[8];
  const float* bfcout = (const float*)d_in[9];
  const float* Wspan = (const float*)d_in[10];
  const float* bspan = (const float*)d_in[11];
  float* out = (float*)d_out;

  char* ws = (char*)d_ws;
  ushort_t* Wg = (ushort_t*)(ws);                // 4096*1536*2 = 12582912
  ushort_t* Wfc = (ushort_t*)(ws + 12582912);    // 512*1024*2  =  1048576
  float* bg = (float*)(ws + 13631488);           // 4096*4      =    16384
  ushort_t* XA = (ushort_t*)(ws + 13647872);     // 12582912
  ushort_t* XB = (ushort_t*)(ws + 26230784);     // 12582912
  float* cbuf = (float*)(ws + 38813696);         // 16777216 -> total 55590912 B

  prep_gates_w<<<(BSZ * XLD) / 256, 256, 0, stream>>>(Wih, Whh, bih, bhh, Wg, bg);
  prep_fcin_w<<<(INPD * HID) / 256, 256, 0, stream>>>(Wfcin, Wfc);
  init_kernel<<<(BSZ * HID) / 256, 256, 0, stream>>>(hx, cx, XA, cbuf);
  span_kernel<<<(BSZ * NSPAN) / 256, 256, 0, stream>>>(hx, Wspan, bspan, out);

  float* outp = out + BSZ * NSPAN;
  for (int t = 0; t < NDAYS; ++t) {
    ushort_t* Xin = (t & 1) ? XB : XA;
    ushort_t* Xout = (t & 1) ? XA : XB;
    gates128_kernel<<<dim3(32, 32), 256, 0, stream>>>(Xin, Wg, bg, cbuf, Xout);
    if (t < NDAYS - 1) {
      // fcin also computes+writes fcout for this t (by==0 blocks)
      fcin128_kernel<<<dim3(32, 4), 256, 0, stream>>>(Xout + INPD, Wfc, bfcin, Xout,
                                                      Wfcout, bfcout, outp, t);
    } else {
      fcout_kernel<<<BSZ / 4, 256, 0, stream>>>(Xout, Wfcout, bfcout, outp, t);
    }
  }
}

// Round 6
// 1997.925 us; speedup vs baseline: 1.8242x; 1.8242x over previous
//
#include <hip/hip_runtime.h>

typedef __bf16 bf16x8 __attribute__((ext_vector_type(8)));
typedef float f32x4 __attribute__((ext_vector_type(4)));
typedef unsigned short ushort_t;
typedef unsigned short u16x8 __attribute__((ext_vector_type(8)));

#define BSZ 4096
#define HID 1024
#define INPD 512
#define NSPAN 8
#define NOUT 2
#define NDAYS 20
#define XLD 1536  // X = [inp(512) | h(1024)] K-dim

// Frag-order layout: element (row, k) of a [R][K] bf16 matrix lives at
//   ((row>>4)*(K/32) + (k>>5))*512 + ((k&31)>>3)*128 + (row&15)*8 + (k&7)
// so each 16x32 MFMA fragment is 1KB contiguous, slot li = ((k&31)>>3)*16+(row&15)
// holds 8 k-consecutive elements -> exactly the mfma_16x16x32 operand mapping.

__device__ __forceinline__ ushort_t f2bf(float f) {
  union { float f; unsigned u; } v; v.f = f;
  unsigned r = v.u + 0x7FFFu + ((v.u >> 16) & 1u);
  return (ushort_t)(r >> 16);
}
__device__ __forceinline__ float bf2f(ushort_t b) {
  union { unsigned u; float f; } v; v.u = ((unsigned)b) << 16;
  return v.f;
}
__device__ __forceinline__ float sigf(float x) { return 1.f / (1.f + __expf(-x)); }
__device__ __forceinline__ float tanhfast(float x) { return 2.f / (1.f + __expf(-2.f * x)) - 1.f; }

__device__ __forceinline__ void gload16(const void* g, void* l) {
  __builtin_amdgcn_global_load_lds((const __attribute__((address_space(1))) void*)g,
                                   (__attribute__((address_space(3))) void*)l, 16, 0, 0);
}

// ---------------------------------------------------------------------------
// Wg prep -> frag-order. Gate-reordered row r_perm = (j/16)*64 + gate*16 + (j%16).
// Thread per 8-elem slot: gid over 4096*1536/8 = 786432.
// ---------------------------------------------------------------------------
__global__ void prep_gates_w(const float* __restrict__ Wih, const float* __restrict__ Whh,
                             const float* __restrict__ bih, const float* __restrict__ bhh,
                             ushort_t* __restrict__ Wgf, float* __restrict__ bg) {
  int gid = blockIdx.x * 256 + threadIdx.x;
  int rb = gid / 3072;           // 48*64
  int rem = gid - rb * 3072;
  int kk = rem >> 6;
  int li = rem & 63;
  int rp = rb * 16 + (li & 15);
  int kb = kk * 32 + ((li >> 4) << 3);
  int g = (rp >> 4) & 3;
  int j = (rp >> 6) * 16 + (rp & 15);
  int src = g * HID + j;
  const float* s = (kb < INPD) ? (Wih + (size_t)src * INPD + kb)
                               : (Whh + (size_t)src * HID + (kb - INPD));
  u16x8 o;
#pragma unroll
  for (int e = 0; e < 8; ++e) o[e] = f2bf(s[e]);
  *(u16x8*)(Wgf + (size_t)gid * 8) = o;
  if (kk == 0 && li < 16) bg[rp] = bih[src] + bhh[src];
}

// Wfcin prep -> frag-order [512][1024]; gid over 512*1024/8 = 65536
__global__ void prep_fcin_w(const float* __restrict__ W, ushort_t* __restrict__ Wf) {
  int gid = blockIdx.x * 256 + threadIdx.x;
  int rb = gid / 2048;           // 32*64
  int rem = gid - rb * 2048;
  int kk = rem >> 6;
  int li = rem & 63;
  int row = rb * 16 + (li & 15);
  int kb = kk * 32 + ((li >> 4) << 3);
  const float* s = W + (size_t)row * HID + kb;
  u16x8 o;
#pragma unroll
  for (int e = 0; e < 8; ++e) o[e] = f2bf(s[e]);
  *(u16x8*)(Wf + (size_t)gid * 8) = o;
}

// X init (frag-order): inp part zeros, h part = bf16(hx). gid over 786432.
__global__ void init_x(const float* __restrict__ hx, ushort_t* __restrict__ Xf) {
  int gid = blockIdx.x * 256 + threadIdx.x;
  int rb = gid / 3072;
  int rem = gid - rb * 3072;
  int kk = rem >> 6;
  int li = rem & 63;
  int row = rb * 16 + (li & 15);
  int kb = kk * 32 + ((li >> 4) << 3);
  u16x8 o;
  if (kb < INPD) {
#pragma unroll
    for (int e = 0; e < 8; ++e) o[e] = 0;
  } else {
    const float* s = hx + (size_t)row * HID + (kb - INPD);
#pragma unroll
    for (int e = 0; e < 8; ++e) o[e] = f2bf(s[e]);
  }
  *(u16x8*)(Xf + (size_t)gid * 8) = o;
}

// num_spans = softmax(hx @ W_span.T + b_span), fp32
__global__ void span_kernel(const float* __restrict__ hx, const float* __restrict__ Wspan,
                            const float* __restrict__ bspan, float* __restrict__ out) {
  int gid = blockIdx.x * 256 + threadIdx.x;  // over 4096*8
  int b = gid >> 3, o = gid & 7;
  const float4* hr = (const float4*)(hx + (size_t)b * HID);
  const float4* wr = (const float4*)(Wspan + (size_t)o * HID);
  float acc = 0.f;
  for (int i = 0; i < HID / 4; ++i) {
    float4 h = hr[i], w = wr[i];
    acc += h.x * w.x + h.y * w.y + h.z * w.z + h.w * w.w;
  }
  acc += bspan[o];
  float m = acc;
  for (int s = 1; s < 8; s <<= 1) m = fmaxf(m, __shfl_xor(m, s));
  float e = __expf(acc - m);
  float ssum = e;
  for (int s = 1; s < 8; s <<= 1) ssum += __shfl_xor(ssum, s);
  out[gid] = e / ssum;
}

// standalone fcout (only t = NDAYS-1), reads frag-order X
__global__ void fcout_kernel(const ushort_t* __restrict__ Xf, const float* __restrict__ W,
                             const float* __restrict__ bvec, float* __restrict__ outp, int t) {
  const int lane = threadIdx.x & 63;
  const int wave = threadIdx.x >> 6;
  const int b = blockIdx.x * 4 + wave;
  const int rb = b >> 4, r = b & 15;
  const int kk = 16 + (lane >> 1);
  const int ss = (lane & 1) * 2;
  const size_t base = ((size_t)rb * 48 + kk) * 512 + (ss * 16 + r) * 8;
  u16x8 h0 = *(const u16x8*)(Xf + base);        // j = lane*16 .. +8
  u16x8 h1 = *(const u16x8*)(Xf + base + 128);  // j = lane*16+8 .. +16
  const float* w0 = W + lane * 16;
  const float* w1 = W + HID + lane * 16;
  float l0 = 0.f, l1 = 0.f;
#pragma unroll
  for (int j = 0; j < 8; ++j) {
    float ha = bf2f(h0[j]);
    l0 += ha * w0[j];
    l1 += ha * w1[j];
    float hb = bf2f(h1[j]);
    l0 += hb * w0[j + 8];
    l1 += hb * w1[j + 8];
  }
#pragma unroll
  for (int s = 32; s > 0; s >>= 1) {
    l0 += __shfl_xor(l0, s);
    l1 += __shfl_xor(l1, s);
  }
  if (lane == 0) {
    l0 += bvec[0];
    l1 += bvec[1];
    float m = fmaxf(l0, l1);
    float e0 = __expf(l0 - m), e1 = __expf(l1 - m);
    float inv = 1.f / (e0 + e1);
    float* o = outp + (size_t)b * (NDAYS * NOUT) + t * NOUT;
    o[0] = e0 * inv;
    o[1] = e1 * inv;
  }
}

// ---------------------------------------------------------------------------
// Gates GEMM: 128x128 / BK=32 / 4-wave (R2's proven multi-block structure).
// Both operands frag-order in global -> every gload_lds is 1KB lane-linear;
// LDS frag-linear -> zero-conflict ds_read_b128. Fused LSTM epilogue.
// ---------------------------------------------------------------------------
__global__ void gates128_kernel(const ushort_t* __restrict__ A,
                                const ushort_t* __restrict__ B,
                                const float* __restrict__ bias, float* __restrict__ cbuf,
                                ushort_t* __restrict__ hout) {
  __shared__ __align__(16) ushort_t ldsA[8 * 512];
  __shared__ __align__(16) ushort_t ldsB[8 * 512];
  const int tid = threadIdx.x;
  const int lane = tid & 63;
  const int wave = tid >> 6;

  // XCD-aware bijective swizzle (nwg = 1024, %8==0)
  int bid = blockIdx.y * gridDim.x + blockIdx.x;
  int nwg = gridDim.x * gridDim.y;
  int cpx = nwg >> 3;
  int swz = (bid & 7) * cpx + (bid >> 3);
  int bx = swz % gridDim.x;
  int by = swz / gridDim.x;
  const int bm = bx * 128;
  const int bn = by * 128;
  const int wm = (wave >> 1) * 64;
  const int wn = (wave & 1) * 64;

  f32x4 acc[4][4] = {};

  // staging: wave w stages frags {2w, 2w+1}; source is 1KB contiguous/frag
  const int f0 = wave * 2, f1 = wave * 2 + 1;
  const ushort_t* gA0 = A + ((size_t)((bm >> 4) + f0) * 48) * 512 + lane * 8;
  const ushort_t* gA1 = A + ((size_t)((bm >> 4) + f1) * 48) * 512 + lane * 8;
  const ushort_t* gB0 = B + ((size_t)((bn >> 4) + f0) * 48) * 512 + lane * 8;
  const ushort_t* gB1 = B + ((size_t)((bn >> 4) + f1) * 48) * 512 + lane * 8;

  for (int kk = 0; kk < 48; ++kk) {
    const int ko = kk * 512;
    gload16(gA0 + ko, ldsA + f0 * 512);
    gload16(gA1 + ko, ldsA + f1 * 512);
    gload16(gB0 + ko, ldsB + f0 * 512);
    gload16(gB1 + ko, ldsB + f1 * 512);
    __syncthreads();

    bf16x8 af[4], bf[4];
#pragma unroll
    for (int i = 0; i < 4; ++i) {
      af[i] = *(const bf16x8*)(ldsA + ((wm >> 4) + i) * 512 + lane * 8);
      bf[i] = *(const bf16x8*)(ldsB + ((wn >> 4) + i) * 512 + lane * 8);
    }
#pragma unroll
    for (int mi = 0; mi < 4; ++mi)
#pragma unroll
      for (int ni = 0; ni < 4; ++ni)
        acc[mi][ni] = __builtin_amdgcn_mfma_f32_16x16x32_bf16(af[mi], bf[ni], acc[mi][ni], 0, 0, 0);
    __syncthreads();
  }

  // fused LSTM epilogue; h written to frag-order X
  const int colbase = bn + wn;  // multiple of 64
  const int jj = (colbase >> 6) * 16 + (lane & 15);
  const int cb = colbase + (lane & 15);
  const float bI = bias[cb];
  const float bF = bias[cb + 16];
  const float bG = bias[cb + 32];
  const float bO = bias[cb + 48];
  const size_t kpart = (size_t)(16 + (jj >> 5)) * 512 + ((jj & 31) >> 3) * 128 + (jj & 7);
  const int q4 = (lane >> 4) << 2;
#pragma unroll
  for (int mi = 0; mi < 4; ++mi) {
    const size_t rowbase = (size_t)(((bm + wm) >> 4) + mi) * 24576 + kpart;
#pragma unroll
    for (int r = 0; r < 4; ++r) {
      const int b = bm + wm + mi * 16 + q4 + r;
      float ig = sigf(acc[mi][0][r] + bI);
      float fg = sigf(acc[mi][1][r] + bF);
      float gg = tanhfast(acc[mi][2][r] + bG);
      float og = sigf(acc[mi][3][r] + bO);
      size_t cidx = (size_t)b * HID + jj;
      float cn = fg * cbuf[cidx] + ig * gg;
      cbuf[cidx] = cn;
      hout[rowbase + (q4 + r) * 8] = f2bf(og * tanhfast(cn));
    }
  }
}

// ---------------------------------------------------------------------------
// fcin GEMM (frag-order, 128x128, K=1024) with fused fcout on by==0 blocks.
// A = h-part of X (kk 16..47), B = Wfc frag-order. relu+bias -> inp part of X.
// ---------------------------------------------------------------------------
__global__ void fcin128_kernel(const ushort_t* __restrict__ Xf,
                               const ushort_t* __restrict__ B,
                               const float* __restrict__ bias, ushort_t* __restrict__ hout,
                               const float* __restrict__ Wout, const float* __restrict__ bout,
                               float* __restrict__ outp, int t) {
  __shared__ __align__(16) ushort_t ldsA[8 * 512];
  __shared__ __align__(16) ushort_t ldsB[8 * 512];
  const int tid = threadIdx.x;
  const int lane = tid & 63;
  const int wave = tid >> 6;

  int bid = blockIdx.y * gridDim.x + blockIdx.x;  // nwg = 128, %8==0
  int nwg = gridDim.x * gridDim.y;
  int cpx = nwg >> 3;
  int swz = (bid & 7) * cpx + (bid >> 3);
  int bx = swz % gridDim.x;
  int by = swz / gridDim.x;
  const int bm = bx * 128;
  const int bn = by * 128;
  const int wm = (wave >> 1) * 64;
  const int wn = (wave & 1) * 64;
  const bool doOut = (by == 0);

  f32x4 acc[4][4] = {};
  float lo0 = 0.f, lo1 = 0.f;
  const int orow = tid >> 1, okh = tid & 1;
  const int ofr = orow >> 4, orw = orow & 15;

  const int f0 = wave * 2, f1 = wave * 2 + 1;
  // A rows bm.., k 512..1535 -> kk 16..47 of X
  const ushort_t* gA0 = Xf + ((size_t)((bm >> 4) + f0) * 48 + 16) * 512 + lane * 8;
  const ushort_t* gA1 = Xf + ((size_t)((bm >> 4) + f1) * 48 + 16) * 512 + lane * 8;
  const ushort_t* gB0 = B + ((size_t)((bn >> 4) + f0) * 32) * 512 + lane * 8;
  const ushort_t* gB1 = B + ((size_t)((bn >> 4) + f1) * 32) * 512 + lane * 8;

  for (int kk = 0; kk < 32; ++kk) {
    const int ko = kk * 512;
    gload16(gA0 + ko, ldsA + f0 * 512);
    gload16(gA1 + ko, ldsA + f1 * 512);
    gload16(gB0 + ko, ldsB + f0 * 512);
    gload16(gB1 + ko, ldsB + f1 * 512);
    __syncthreads();

    bf16x8 af[4], bf[4];
#pragma unroll
    for (int i = 0; i < 4; ++i) {
      af[i] = *(const bf16x8*)(ldsA + ((wm >> 4) + i) * 512 + lane * 8);
      bf[i] = *(const bf16x8*)(ldsB + ((wn >> 4) + i) * 512 + lane * 8);
    }
#pragma unroll
    for (int mi = 0; mi < 4; ++mi)
#pragma unroll
      for (int ni = 0; ni < 4; ++ni)
        acc[mi][ni] = __builtin_amdgcn_mfma_f32_16x16x32_bf16(af[mi], bf[ni], acc[mi][ni], 0, 0, 0);

    if (doOut) {
      // row orow, j = kk*32 + okh*16 .. +16: slots (okh*2)*16+orw, (okh*2+1)*16+orw
      u16x8 h0 = *(const u16x8*)(ldsA + ofr * 512 + ((okh * 2) * 16 + orw) * 8);
      u16x8 h1 = *(const u16x8*)(ldsA + ofr * 512 + ((okh * 2 + 1) * 16 + orw) * 8);
      const float* w0 = Wout + kk * 32 + okh * 16;
      const float* w1 = Wout + HID + kk * 32 + okh * 16;
#pragma unroll
      for (int j = 0; j < 8; ++j) {
        float ha = bf2f(h0[j]), hb = bf2f(h1[j]);
        lo0 += ha * w0[j] + hb * w0[j + 8];
        lo1 += ha * w1[j] + hb * w1[j + 8];
      }
    }
    __syncthreads();
  }

  // relu+bias -> inp part of X (k = n, 0..511), frag-order
  const int q4 = (lane >> 4) << 2;
#pragma unroll
  for (int mi = 0; mi < 4; ++mi) {
    const size_t rowbase = (size_t)(((bm + wm) >> 4) + mi) * 24576;
#pragma unroll
    for (int ni = 0; ni < 4; ++ni) {
      const int n = bn + wn + ni * 16 + (lane & 15);
      const float bb = bias[n];
      const size_t kpart = (size_t)(n >> 5) * 512 + ((n & 31) >> 3) * 128 + (n & 7);
#pragma unroll
      for (int r = 0; r < 4; ++r) {
        float v = fmaxf(acc[mi][ni][r] + bb, 0.f);
        hout[rowbase + kpart + (q4 + r) * 8] = f2bf(v);
      }
    }
  }

  if (doOut) {
    lo0 += __shfl_xor(lo0, 1);
    lo1 += __shfl_xor(lo1, 1);
    if (okh == 0) {
      float l0 = lo0 + bout[0];
      float l1 = lo1 + bout[1];
      float m = fmaxf(l0, l1);
      float e0 = __expf(l0 - m), e1 = __expf(l1 - m);
      float inv = 1.f / (e0 + e1);
      float* o = outp + (size_t)(bm + orow) * (NDAYS * NOUT) + t * NOUT;
      o[0] = e0 * inv;
      o[1] = e1 * inv;
    }
  }
}

extern "C" void kernel_launch(void* const* d_in, const int* in_sizes, int n_in, void* d_out,
                              int out_size, void* d_ws, size_t ws_size, hipStream_t stream) {
  const float* hx = (const float*)d_in[0];
  const float* cx = (const float*)d_in[1];
  const float* Wih = (const float*)d_in[2];
  const float* Whh = (const float*)d_in[3];
  const float* bih = (const float*)d_in[4];
  const float* bhh = (const float*)d_in[5];
  const float* Wfcin = (const float*)d_in[6];
  const float* bfcin = (const float*)d_in[7];
  const float* Wfcout = (const float*)d_in[8];
  const float* bfcout = (const float*)d_in[9];
  const float* Wspan = (const float*)d_in[10];
  const float* bspan = (const float*)d_in[11];
  float* out = (float*)d_out;

  char* ws = (char*)d_ws;
  ushort_t* Wgf = (ushort_t*)(ws);               // 4096*1536*2 = 12582912
  ushort_t* Wfcf = (ushort_t*)(ws + 12582912);   // 512*1024*2  =  1048576
  float* bg = (float*)(ws + 13631488);           // 4096*4      =    16384
  ushort_t* XA = (ushort_t*)(ws + 13647872);     // 12582912
  ushort_t* XB = (ushort_t*)(ws + 26230784);     // 12582912
  float* cbuf = (float*)(ws + 38813696);         // 16777216 -> total 55590912 B

  prep_gates_w<<<3072, 256, 0, stream>>>(Wih, Whh, bih, bhh, Wgf, bg);
  prep_fcin_w<<<256, 256, 0, stream>>>(Wfcin, Wfcf);
  init_x<<<3072, 256, 0, stream>>>(hx, XA);
  hipMemcpyAsync(cbuf, cx, (size_t)BSZ * HID * 4, hipMemcpyDeviceToDevice, stream);
  span_kernel<<<(BSZ * NSPAN) / 256, 256, 0, stream>>>(hx, Wspan, bspan, out);

  float* outp = out + BSZ * NSPAN;
  for (int t = 0; t < NDAYS; ++t) {
    ushort_t* Xin = (t & 1) ? XB : XA;
    ushort_t* Xout = (t & 1) ? XA : XB;
    gates128_kernel<<<dim3(32, 32), 256, 0, stream>>>(Xin, Wgf, bg, cbuf, Xout);
    if (t < NDAYS - 1) {
      fcin128_kernel<<<dim3(32, 4), 256, 0, stream>>>(Xout, Wfcf, bfcin, Xout,
                                                      Wfcout, bfcout, outp, t);
    } else {
      fcout_kernel<<<BSZ / 4, 256, 0, stream>>>(Xout, Wfcout, bfcout, outp, t);
    }
  }
}

// Round 7
// 1554.305 us; speedup vs baseline: 2.3449x; 1.2854x over previous
//
#include <hip/hip_runtime.h>

typedef __bf16 bf16x8 __attribute__((ext_vector_type(8)));
typedef float f32x4 __attribute__((ext_vector_type(4)));
typedef unsigned short ushort_t;
typedef unsigned short u16x8 __attribute__((ext_vector_type(8)));

#define BSZ 4096
#define HID 1024
#define INPD 512
#define NSPAN 8
#define NOUT 2
#define NDAYS 20
#define XLD 1536  // X = [inp(512) | h(1024)] K-dim

// Frag-order layout: element (row, k) of a [R][K] bf16 matrix lives at
//   ((row>>4)*(K/32) + (k>>5))*512 + ((k&31)>>3)*128 + (row&15)*8 + (k&7)
// so each 16x32 MFMA fragment is 1KB contiguous, slot li = ((k&31)>>3)*16+(row&15)
// holds 8 k-consecutive elements -> exactly the mfma_16x16x32 operand mapping.

__device__ __forceinline__ ushort_t f2bf(float f) {
  union { float f; unsigned u; } v; v.f = f;
  unsigned r = v.u + 0x7FFFu + ((v.u >> 16) & 1u);
  return (ushort_t)(r >> 16);
}
__device__ __forceinline__ float bf2f(ushort_t b) {
  union { unsigned u; float f; } v; v.u = ((unsigned)b) << 16;
  return v.f;
}
__device__ __forceinline__ float sigf(float x) { return 1.f / (1.f + __expf(-x)); }
__device__ __forceinline__ float tanhfast(float x) { return 2.f / (1.f + __expf(-2.f * x)) - 1.f; }

__device__ __forceinline__ void gload16(const void* g, void* l) {
  __builtin_amdgcn_global_load_lds((const __attribute__((address_space(1))) void*)g,
                                   (__attribute__((address_space(3))) void*)l, 16, 0, 0);
}

// ---------------------------------------------------------------------------
// Wg prep -> frag-order. Gate-reordered row r_perm = (j/16)*64 + gate*16 + (j%16).
// ---------------------------------------------------------------------------
__global__ void prep_gates_w(const float* __restrict__ Wih, const float* __restrict__ Whh,
                             const float* __restrict__ bih, const float* __restrict__ bhh,
                             ushort_t* __restrict__ Wgf, float* __restrict__ bg) {
  int gid = blockIdx.x * 256 + threadIdx.x;
  int rb = gid / 3072;           // 48*64
  int rem = gid - rb * 3072;
  int kk = rem >> 6;
  int li = rem & 63;
  int rp = rb * 16 + (li & 15);
  int kb = kk * 32 + ((li >> 4) << 3);
  int g = (rp >> 4) & 3;
  int j = (rp >> 6) * 16 + (rp & 15);
  int src = g * HID + j;
  const float* s = (kb < INPD) ? (Wih + (size_t)src * INPD + kb)
                               : (Whh + (size_t)src * HID + (kb - INPD));
  u16x8 o;
#pragma unroll
  for (int e = 0; e < 8; ++e) o[e] = f2bf(s[e]);
  *(u16x8*)(Wgf + (size_t)gid * 8) = o;
  if (kk == 0 && li < 16) bg[rp] = bih[src] + bhh[src];
}

// Wfcin prep -> frag-order [512][1024]
__global__ void prep_fcin_w(const float* __restrict__ W, ushort_t* __restrict__ Wf) {
  int gid = blockIdx.x * 256 + threadIdx.x;
  int rb = gid / 2048;           // 32*64
  int rem = gid - rb * 2048;
  int kk = rem >> 6;
  int li = rem & 63;
  int row = rb * 16 + (li & 15);
  int kb = kk * 32 + ((li >> 4) << 3);
  const float* s = W + (size_t)row * HID + kb;
  u16x8 o;
#pragma unroll
  for (int e = 0; e < 8; ++e) o[e] = f2bf(s[e]);
  *(u16x8*)(Wf + (size_t)gid * 8) = o;
}

// X init (frag-order): inp part zeros, h part = bf16(hx)
__global__ void init_x(const float* __restrict__ hx, ushort_t* __restrict__ Xf) {
  int gid = blockIdx.x * 256 + threadIdx.x;
  int rb = gid / 3072;
  int rem = gid - rb * 3072;
  int kk = rem >> 6;
  int li = rem & 63;
  int row = rb * 16 + (li & 15);
  int kb = kk * 32 + ((li >> 4) << 3);
  u16x8 o;
  if (kb < INPD) {
#pragma unroll
    for (int e = 0; e < 8; ++e) o[e] = 0;
  } else {
    const float* s = hx + (size_t)row * HID + (kb - INPD);
#pragma unroll
    for (int e = 0; e < 8; ++e) o[e] = f2bf(s[e]);
  }
  *(u16x8*)(Xf + (size_t)gid * 8) = o;
}

// num_spans = softmax(hx @ W_span.T + b_span), fp32
__global__ void span_kernel(const float* __restrict__ hx, const float* __restrict__ Wspan,
                            const float* __restrict__ bspan, float* __restrict__ out) {
  int gid = blockIdx.x * 256 + threadIdx.x;  // over 4096*8
  int b = gid >> 3, o = gid & 7;
  const float4* hr = (const float4*)(hx + (size_t)b * HID);
  const float4* wr = (const float4*)(Wspan + (size_t)o * HID);
  float acc = 0.f;
  for (int i = 0; i < HID / 4; ++i) {
    float4 h = hr[i], w = wr[i];
    acc += h.x * w.x + h.y * w.y + h.z * w.z + h.w * w.w;
  }
  acc += bspan[o];
  float m = acc;
  for (int s = 1; s < 8; s <<= 1) m = fmaxf(m, __shfl_xor(m, s));
  float e = __expf(acc - m);
  float ssum = e;
  for (int s = 1; s < 8; s <<= 1) ssum += __shfl_xor(ssum, s);
  out[gid] = e / ssum;
}

// standalone fcout (only t = NDAYS-1), reads frag-order X
__global__ void fcout_kernel(const ushort_t* __restrict__ Xf, const float* __restrict__ W,
                             const float* __restrict__ bvec, float* __restrict__ outp, int t) {
  const int lane = threadIdx.x & 63;
  const int wave = threadIdx.x >> 6;
  const int b = blockIdx.x * 4 + wave;
  const int rb = b >> 4, r = b & 15;
  const int kk = 16 + (lane >> 1);
  const int ss = (lane & 1) * 2;
  const size_t base = ((size_t)rb * 48 + kk) * 512 + (ss * 16 + r) * 8;
  u16x8 h0 = *(const u16x8*)(Xf + base);
  u16x8 h1 = *(const u16x8*)(Xf + base + 128);
  const float* w0 = W + lane * 16;
  const float* w1 = W + HID + lane * 16;
  float l0 = 0.f, l1 = 0.f;
#pragma unroll
  for (int j = 0; j < 8; ++j) {
    float ha = bf2f(h0[j]);
    l0 += ha * w0[j];
    l1 += ha * w1[j];
    float hb = bf2f(h1[j]);
    l0 += hb * w0[j + 8];
    l1 += hb * w1[j + 8];
  }
#pragma unroll
  for (int s = 32; s > 0; s >>= 1) {
    l0 += __shfl_xor(l0, s);
    l1 += __shfl_xor(l1, s);
  }
  if (lane == 0) {
    l0 += bvec[0];
    l1 += bvec[1];
    float m = fmaxf(l0, l1);
    float e0 = __expf(l0 - m), e1 = __expf(l1 - m);
    float inv = 1.f / (e0 + e1);
    float* o = outp + (size_t)b * (NDAYS * NOUT) + t * NOUT;
    o[0] = e0 * inv;
    o[1] = e1 * inv;
  }
}

// ---------------------------------------------------------------------------
// Gates GEMM: 128x128 / BK=32 / 4-wave, frag-order operands, frag-linear LDS.
// UNCHANGED from R6 (59.5 us = 866 TF, at the m97-structure ceiling).
// ---------------------------------------------------------------------------
__global__ void gates128_kernel(const ushort_t* __restrict__ A,
                                const ushort_t* __restrict__ B,
                                const float* __restrict__ bias, float* __restrict__ cbuf,
                                ushort_t* __restrict__ hout) {
  __shared__ __align__(16) ushort_t ldsA[8 * 512];
  __shared__ __align__(16) ushort_t ldsB[8 * 512];
  const int tid = threadIdx.x;
  const int lane = tid & 63;
  const int wave = tid >> 6;

  int bid = blockIdx.y * gridDim.x + blockIdx.x;
  int nwg = gridDim.x * gridDim.y;
  int cpx = nwg >> 3;
  int swz = (bid & 7) * cpx + (bid >> 3);
  int bx = swz % gridDim.x;
  int by = swz / gridDim.x;
  const int bm = bx * 128;
  const int bn = by * 128;
  const int wm = (wave >> 1) * 64;
  const int wn = (wave & 1) * 64;

  f32x4 acc[4][4] = {};

  const int f0 = wave * 2, f1 = wave * 2 + 1;
  const ushort_t* gA0 = A + ((size_t)((bm >> 4) + f0) * 48) * 512 + lane * 8;
  const ushort_t* gA1 = A + ((size_t)((bm >> 4) + f1) * 48) * 512 + lane * 8;
  const ushort_t* gB0 = B + ((size_t)((bn >> 4) + f0) * 48) * 512 + lane * 8;
  const ushort_t* gB1 = B + ((size_t)((bn >> 4) + f1) * 48) * 512 + lane * 8;

  for (int kk = 0; kk < 48; ++kk) {
    const int ko = kk * 512;
    gload16(gA0 + ko, ldsA + f0 * 512);
    gload16(gA1 + ko, ldsA + f1 * 512);
    gload16(gB0 + ko, ldsB + f0 * 512);
    gload16(gB1 + ko, ldsB + f1 * 512);
    __syncthreads();

    bf16x8 af[4], bf[4];
#pragma unroll
    for (int i = 0; i < 4; ++i) {
      af[i] = *(const bf16x8*)(ldsA + ((wm >> 4) + i) * 512 + lane * 8);
      bf[i] = *(const bf16x8*)(ldsB + ((wn >> 4) + i) * 512 + lane * 8);
    }
#pragma unroll
    for (int mi = 0; mi < 4; ++mi)
#pragma unroll
      for (int ni = 0; ni < 4; ++ni)
        acc[mi][ni] = __builtin_amdgcn_mfma_f32_16x16x32_bf16(af[mi], bf[ni], acc[mi][ni], 0, 0, 0);
    __syncthreads();
  }

  const int colbase = bn + wn;
  const int jj = (colbase >> 6) * 16 + (lane & 15);
  const int cb = colbase + (lane & 15);
  const float bI = bias[cb];
  const float bF = bias[cb + 16];
  const float bG = bias[cb + 32];
  const float bO = bias[cb + 48];
  const size_t kpart = (size_t)(16 + (jj >> 5)) * 512 + ((jj & 31) >> 3) * 128 + (jj & 7);
  const int q4 = (lane >> 4) << 2;
#pragma unroll
  for (int mi = 0; mi < 4; ++mi) {
    const size_t rowbase = (size_t)(((bm + wm) >> 4) + mi) * 24576 + kpart;
#pragma unroll
    for (int r = 0; r < 4; ++r) {
      const int b = bm + wm + mi * 16 + q4 + r;
      float ig = sigf(acc[mi][0][r] + bI);
      float fg = sigf(acc[mi][1][r] + bF);
      float gg = tanhfast(acc[mi][2][r] + bG);
      float og = sigf(acc[mi][3][r] + bO);
      size_t cidx = (size_t)b * HID + jj;
      float cn = fg * cbuf[cidx] + ig * gg;
      cbuf[cidx] = cn;
      hout[rowbase + (q4 + r) * 8] = f2bf(og * tanhfast(cn));
    }
  }
}

// ---------------------------------------------------------------------------
// fcin GEMM: 64x128 tiles -> 256 blocks (full GPU), double-buffered LDS with
// distance-2 prefetch + counted vmcnt(3) (no full drain in steady state).
// 4 waves as 2Mx2N, each 32x64 (2x4 frags, 8 MFMA : 6 ds_reads per iter).
// Fused fcout on by==0 blocks with Wfcout staged in LDS once.
// A = h-part of X (kk 16..47), B = Wfc frag-order; relu+bias -> inp part of X.
// ---------------------------------------------------------------------------
__global__ void fcin64_kernel(const ushort_t* __restrict__ Xf,
                              const ushort_t* __restrict__ B,
                              const float* __restrict__ bias, ushort_t* __restrict__ hout,
                              const float* __restrict__ Wout, const float* __restrict__ bout,
                              float* __restrict__ outp, int t) {
  __shared__ __align__(16) ushort_t ldsA[2][4 * 512];
  __shared__ __align__(16) ushort_t ldsB[2][8 * 512];
  __shared__ float ldsW[2048];
  const int tid = threadIdx.x;
  const int lane = tid & 63;
  const int wave = tid >> 6;
  const int wmi = wave >> 1;  // 0..1 -> 32-row half
  const int wni = wave & 1;   // 0..1 -> 64-col half

  int bid = blockIdx.y * gridDim.x + blockIdx.x;  // nwg = 256, %8==0
  int nwg = gridDim.x * gridDim.y;
  int cpx = nwg >> 3;
  int swz = (bid & 7) * cpx + (bid >> 3);
  int bx = swz % gridDim.x;
  int by = swz / gridDim.x;
  const int bm = bx * 64;
  const int bn = by * 128;
  const bool doOut = (by == 0);

  // stage Wfcout (2x1024 f32) into LDS first (its vmem loads drain before
  // the frag gloads are issued, keeping vmcnt arithmetic clean)
  {
    float4 w0 = *(const float4*)(Wout + tid * 8);
    float4 w1 = *(const float4*)(Wout + tid * 8 + 4);
    *(float4*)(ldsW + tid * 8) = w0;
    *(float4*)(ldsW + tid * 8 + 4) = w1;
  }

  f32x4 acc[2][4] = {};
  float lo0 = 0.f, lo1 = 0.f;
  const int orow = tid >> 2, okq = tid & 3;  // row 0..63, k-quarter
  const int ofr = orow >> 4, orw = orow & 15;

  // staging: wave w -> A-frag w (1 gload) + B-frags {2w,2w+1} (2 gloads)
  const ushort_t* gA = Xf + ((size_t)((bm >> 4) + wave) * 48 + 16) * 512 + lane * 8;
  const ushort_t* gB0 = B + ((size_t)((bn >> 4) + 2 * wave) * 32) * 512 + lane * 8;
  const ushort_t* gB1 = B + ((size_t)((bn >> 4) + 2 * wave + 1) * 32) * 512 + lane * 8;

  // prologue: stage kk=0 -> buf0, kk=1 -> buf1 (3 gloads each per wave)
  gload16(gA, &ldsA[0][wave * 512]);
  gload16(gB0, &ldsB[0][(2 * wave) * 512]);
  gload16(gB1, &ldsB[0][(2 * wave + 1) * 512]);
  gload16(gA + 512, &ldsA[1][wave * 512]);
  gload16(gB0 + 512, &ldsB[1][(2 * wave) * 512]);
  gload16(gB1 + 512, &ldsB[1][(2 * wave + 1) * 512]);
  asm volatile("s_waitcnt vmcnt(3) lgkmcnt(0)" ::: "memory");
  __builtin_amdgcn_sched_barrier(0);
  __builtin_amdgcn_s_barrier();

  for (int kk = 0; kk < 32; ++kk) {
    const int cur = kk & 1;
    const ushort_t* lA = ldsA[cur];
    const ushort_t* lB = ldsB[cur];

    bf16x8 af[2], bf[4];
#pragma unroll
    for (int m = 0; m < 2; ++m)
      af[m] = *(const bf16x8*)(lA + (wmi * 2 + m) * 512 + lane * 8);
#pragma unroll
    for (int n = 0; n < 4; ++n)
      bf[n] = *(const bf16x8*)(lB + (wni * 4 + n) * 512 + lane * 8);

    if (doOut) {
      // row orow, k = kk*32 + okq*8 + e
      u16x8 h = *(const u16x8*)(lA + ofr * 512 + (okq * 16 + orw) * 8);
      const float* w0 = ldsW + kk * 32 + okq * 8;
      const float* w1 = ldsW + 1024 + kk * 32 + okq * 8;
#pragma unroll
      for (int e = 0; e < 8; ++e) {
        float hv = bf2f(h[e]);
        lo0 += hv * w0[e];
        lo1 += hv * w1[e];
      }
    }

    // all of this wave's LDS reads done; then block-wide barrier
    asm volatile("s_waitcnt lgkmcnt(0)" ::: "memory");
    __builtin_amdgcn_sched_barrier(0);
    __builtin_amdgcn_s_barrier();

    if (kk + 2 < 32) {  // stage kk+2 into buf[cur] (just freed)
      const int ko = (kk + 2) * 512;
      gload16(gA + ko, &ldsA[cur][wave * 512]);
      gload16(gB0 + ko, &ldsB[cur][(2 * wave) * 512]);
      gload16(gB1 + ko, &ldsB[cur][(2 * wave + 1) * 512]);
    }

    __builtin_amdgcn_s_setprio(1);
#pragma unroll
    for (int m = 0; m < 2; ++m)
#pragma unroll
      for (int n = 0; n < 4; ++n)
        acc[m][n] = __builtin_amdgcn_mfma_f32_16x16x32_bf16(af[m], bf[n], acc[m][n], 0, 0, 0);
    __builtin_amdgcn_s_setprio(0);

    if (kk + 2 < 32) {
      asm volatile("s_waitcnt vmcnt(3)" ::: "memory");  // kk+1 landed
    } else if (kk == 30) {
      asm volatile("s_waitcnt vmcnt(0)" ::: "memory");  // drain kk=31
    }
    __builtin_amdgcn_sched_barrier(0);
    if (kk < 31) __builtin_amdgcn_s_barrier();
  }

  // relu+bias -> inp part of X (k = n, 0..511), frag-order
  const int q4 = (lane >> 4) << 2;
#pragma unroll
  for (int mi = 0; mi < 2; ++mi) {
    const size_t rowbase = (size_t)((bm >> 4) + wmi * 2 + mi) * 24576;
#pragma unroll
    for (int ni = 0; ni < 4; ++ni) {
      const int n = bn + wni * 64 + ni * 16 + (lane & 15);
      const float bb = bias[n];
      const size_t kpart = (size_t)(n >> 5) * 512 + ((n & 31) >> 3) * 128 + (n & 7);
#pragma unroll
      for (int r = 0; r < 4; ++r) {
        float v = fmaxf(acc[mi][ni][r] + bb, 0.f);
        hout[rowbase + kpart + (q4 + r) * 8] = f2bf(v);
      }
    }
  }

  if (doOut) {
    lo0 += __shfl_xor(lo0, 1);
    lo1 += __shfl_xor(lo1, 1);
    lo0 += __shfl_xor(lo0, 2);
    lo1 += __shfl_xor(lo1, 2);
    if (okq == 0) {
      float l0 = lo0 + bout[0];
      float l1 = lo1 + bout[1];
      float m = fmaxf(l0, l1);
      float e0 = __expf(l0 - m), e1 = __expf(l1 - m);
      float inv = 1.f / (e0 + e1);
      float* o = outp + (size_t)(bm + orow) * (NDAYS * NOUT) + t * NOUT;
      o[0] = e0 * inv;
      o[1] = e1 * inv;
    }
  }
}

extern "C" void kernel_launch(void* const* d_in, const int* in_sizes, int n_in, void* d_out,
                              int out_size, void* d_ws, size_t ws_size, hipStream_t stream) {
  const float* hx = (const float*)d_in[0];
  const float* cx = (const float*)d_in[1];
  const float* Wih = (const float*)d_in[2];
  const float* Whh = (const float*)d_in[3];
  const float* bih = (const float*)d_in[4];
  const float* bhh = (const float*)d_in[5];
  const float* Wfcin = (const float*)d_in[6];
  const float* bfcin = (const float*)d_in[7];
  const float* Wfcout = (const float*)d_in[8];
  const float* bfcout = (const float*)d_in[9];
  const float* Wspan = (const float*)d_in[10];
  const float* bspan = (const float*)d_in[11];
  float* out = (float*)d_out;

  char* ws = (char*)d_ws;
  ushort_t* Wgf = (ushort_t*)(ws);               // 4096*1536*2 = 12582912
  ushort_t* Wfcf = (ushort_t*)(ws + 12582912);   // 512*1024*2  =  1048576
  float* bg = (float*)(ws + 13631488);           // 4096*4      =    16384
  ushort_t* XA = (ushort_t*)(ws + 13647872);     // 12582912
  ushort_t* XB = (ushort_t*)(ws + 26230784);     // 12582912
  float* cbuf = (float*)(ws + 38813696);         // 16777216 -> total 55590912 B

  prep_gates_w<<<3072, 256, 0, stream>>>(Wih, Whh, bih, bhh, Wgf, bg);
  prep_fcin_w<<<256, 256, 0, stream>>>(Wfcin, Wfcf);
  init_x<<<3072, 256, 0, stream>>>(hx, XA);
  hipMemcpyAsync(cbuf, cx, (size_t)BSZ * HID * 4, hipMemcpyDeviceToDevice, stream);
  span_kernel<<<(BSZ * NSPAN) / 256, 256, 0, stream>>>(hx, Wspan, bspan, out);

  float* outp = out + BSZ * NSPAN;
  for (int t = 0; t < NDAYS; ++t) {
    ushort_t* Xin = (t & 1) ? XB : XA;
    ushort_t* Xout = (t & 1) ? XA : XB;
    gates128_kernel<<<dim3(32, 32), 256, 0, stream>>>(Xin, Wgf, bg, cbuf, Xout);
    if (t < NDAYS - 1) {
      fcin64_kernel<<<dim3(64, 4), 256, 0, stream>>>(Xout, Wfcf, bfcin, Xout,
                                                     Wfcout, bfcout, outp, t);
    } else {
      fcout_kernel<<<BSZ / 4, 256, 0, stream>>>(Xout, Wfcout, bfcout, outp, t);
    }
  }
}

// Round 8
// 1539.841 us; speedup vs baseline: 2.3669x; 1.0094x over previous
//
#include <hip/hip_runtime.h>

typedef __bf16 bf16x8 __attribute__((ext_vector_type(8)));
typedef float f32x4 __attribute__((ext_vector_type(4)));
typedef unsigned short ushort_t;
typedef unsigned short u16x8 __attribute__((ext_vector_type(8)));

#define BSZ 4096
#define HID 1024
#define INPD 512
#define NSPAN 8
#define NOUT 2
#define NDAYS 20
#define XLD 1536  // X = [inp(512) | h(1024)] K-dim

// Frag-order layout: element (row, k) of a [R][K] bf16 matrix lives at
//   ((row>>4)*(K/32) + (k>>5))*512 + ((k&31)>>3)*128 + (row&15)*8 + (k&7)
// each 16x32 MFMA fragment is 1KB contiguous = exact mfma_16x16x32 operand map.

__device__ __forceinline__ ushort_t f2bf(float f) {
  union { float f; unsigned u; } v; v.f = f;
  unsigned r = v.u + 0x7FFFu + ((v.u >> 16) & 1u);
  return (ushort_t)(r >> 16);
}
__device__ __forceinline__ float bf2f(ushort_t b) {
  union { unsigned u; float f; } v; v.u = ((unsigned)b) << 16;
  return v.f;
}
__device__ __forceinline__ float sigf(float x) { return 1.f / (1.f + __expf(-x)); }
__device__ __forceinline__ float tanhfast(float x) { return 2.f / (1.f + __expf(-2.f * x)) - 1.f; }

__device__ __forceinline__ void gload16(const void* g, void* l) {
  __builtin_amdgcn_global_load_lds((const __attribute__((address_space(1))) void*)g,
                                   (__attribute__((address_space(3))) void*)l, 16, 0, 0);
}

// ---------------------------------------------------------------------------
// Wg prep -> frag-order. Gate-reordered row r_perm = (j/16)*64 + gate*16 + (j%16).
// ---------------------------------------------------------------------------
__global__ void prep_gates_w(const float* __restrict__ Wih, const float* __restrict__ Whh,
                             const float* __restrict__ bih, const float* __restrict__ bhh,
                             ushort_t* __restrict__ Wgf, float* __restrict__ bg) {
  int gid = blockIdx.x * 256 + threadIdx.x;
  int rb = gid / 3072;           // 48*64
  int rem = gid - rb * 3072;
  int kk = rem >> 6;
  int li = rem & 63;
  int rp = rb * 16 + (li & 15);
  int kb = kk * 32 + ((li >> 4) << 3);
  int g = (rp >> 4) & 3;
  int j = (rp >> 6) * 16 + (rp & 15);
  int src = g * HID + j;
  const float* s = (kb < INPD) ? (Wih + (size_t)src * INPD + kb)
                               : (Whh + (size_t)src * HID + (kb - INPD));
  u16x8 o;
#pragma unroll
  for (int e = 0; e < 8; ++e) o[e] = f2bf(s[e]);
  *(u16x8*)(Wgf + (size_t)gid * 8) = o;
  if (kk == 0 && li < 16) bg[rp] = bih[src] + bhh[src];
}

// Wfcin prep -> frag-order [512][1024]
__global__ void prep_fcin_w(const float* __restrict__ W, ushort_t* __restrict__ Wf) {
  int gid = blockIdx.x * 256 + threadIdx.x;
  int rb = gid / 2048;           // 32*64
  int rem = gid - rb * 2048;
  int kk = rem >> 6;
  int li = rem & 63;
  int row = rb * 16 + (li & 15);
  int kb = kk * 32 + ((li >> 4) << 3);
  const float* s = W + (size_t)row * HID + kb;
  u16x8 o;
#pragma unroll
  for (int e = 0; e < 8; ++e) o[e] = f2bf(s[e]);
  *(u16x8*)(Wf + (size_t)gid * 8) = o;
}

// X init (frag-order): inp part zeros, h part = bf16(hx)
__global__ void init_x(const float* __restrict__ hx, ushort_t* __restrict__ Xf) {
  int gid = blockIdx.x * 256 + threadIdx.x;
  int rb = gid / 3072;
  int rem = gid - rb * 3072;
  int kk = rem >> 6;
  int li = rem & 63;
  int row = rb * 16 + (li & 15);
  int kb = kk * 32 + ((li >> 4) << 3);
  u16x8 o;
  if (kb < INPD) {
#pragma unroll
    for (int e = 0; e < 8; ++e) o[e] = 0;
  } else {
    const float* s = hx + (size_t)row * HID + (kb - INPD);
#pragma unroll
    for (int e = 0; e < 8; ++e) o[e] = f2bf(s[e]);
  }
  *(u16x8*)(Xf + (size_t)gid * 8) = o;
}

// num_spans = softmax(hx @ W_span.T + b_span), fp32
__global__ void span_kernel(const float* __restrict__ hx, const float* __restrict__ Wspan,
                            const float* __restrict__ bspan, float* __restrict__ out) {
  int gid = blockIdx.x * 256 + threadIdx.x;  // over 4096*8
  int b = gid >> 3, o = gid & 7;
  const float4* hr = (const float4*)(hx + (size_t)b * HID);
  const float4* wr = (const float4*)(Wspan + (size_t)o * HID);
  float acc = 0.f;
  for (int i = 0; i < HID / 4; ++i) {
    float4 h = hr[i], w = wr[i];
    acc += h.x * w.x + h.y * w.y + h.z * w.z + h.w * w.w;
  }
  acc += bspan[o];
  float m = acc;
  for (int s = 1; s < 8; s <<= 1) m = fmaxf(m, __shfl_xor(m, s));
  float e = __expf(acc - m);
  float ssum = e;
  for (int s = 1; s < 8; s <<= 1) ssum += __shfl_xor(ssum, s);
  out[gid] = e / ssum;
}

// standalone fcout (only t = NDAYS-1), reads frag-order X
__global__ void fcout_kernel(const ushort_t* __restrict__ Xf, const float* __restrict__ W,
                             const float* __restrict__ bvec, float* __restrict__ outp, int t) {
  const int lane = threadIdx.x & 63;
  const int wave = threadIdx.x >> 6;
  const int b = blockIdx.x * 4 + wave;
  const int rb = b >> 4, r = b & 15;
  const int kk = 16 + (lane >> 1);
  const int ss = (lane & 1) * 2;
  const size_t base = ((size_t)rb * 48 + kk) * 512 + (ss * 16 + r) * 8;
  u16x8 h0 = *(const u16x8*)(Xf + base);
  u16x8 h1 = *(const u16x8*)(Xf + base + 128);
  const float* w0 = W + lane * 16;
  const float* w1 = W + HID + lane * 16;
  float l0 = 0.f, l1 = 0.f;
#pragma unroll
  for (int j = 0; j < 8; ++j) {
    float ha = bf2f(h0[j]);
    l0 += ha * w0[j];
    l1 += ha * w1[j];
    float hb = bf2f(h1[j]);
    l0 += hb * w0[j + 8];
    l1 += hb * w1[j + 8];
  }
#pragma unroll
  for (int s = 32; s > 0; s >>= 1) {
    l0 += __shfl_xor(l0, s);
    l1 += __shfl_xor(l1, s);
  }
  if (lane == 0) {
    l0 += bvec[0];
    l1 += bvec[1];
    float m = fmaxf(l0, l1);
    float e0 = __expf(l0 - m), e1 = __expf(l1 - m);
    float inv = 1.f / (e0 + e1);
    float* o = outp + (size_t)b * (NDAYS * NOUT) + t * NOUT;
    o[0] = e0 * inv;
    o[1] = e1 * inv;
  }
}

// ---------------------------------------------------------------------------
// Gates GEMM, m201-faithful 8-phase: 256x256, BK=64, 8 waves (2M x 4N),
// buf0 = even K-tiles, buf1 = odd K-tiles, one half-tile staged per phase
// (2 gload16/thread), vmcnt(4) at P4 and P8 only.
// Consumption proofs (block-wide, via the end-of-phase barriers):
//   buf B(t) consumed end-P2 -> B(t+2) staged P3/P4 (even) or P7/P8 (odd)
//   buf A(t) consumed end-P3 -> A(t+2) staged P5/P6 (even) or P1/P2 next (odd)
// vmcnt(4)@P4: retires P1,P2 stages -> A(odd tile) landed before P5 reads.
// vmcnt(4)@P8: retires P5,P6 stages -> A(even tile) landed before next P1.
// ---------------------------------------------------------------------------
#define RD_A(BUFA, MH)                                                            \
  _Pragma("unroll") for (int m_ = 0; m_ < 4; ++m_)                                \
  _Pragma("unroll") for (int kk_ = 0; kk_ < 2; ++kk_)                             \
    af[m_][kk_] = *(const bf16x8*)&BUFA[(((wmi8 + (MH)*4 + m_) * 2 + kk_) << 9) + lane8];

#define RD_B(BUFB, NH)                                                            \
  _Pragma("unroll") for (int n_ = 0; n_ < 2; ++n_)                                \
  _Pragma("unroll") for (int kk_ = 0; kk_ < 2; ++kk_)                             \
    bfr[(NH)*2 + n_][kk_] = *(const bf16x8*)&BUFB[(((wni4 + (NH)*2 + n_) * 2 + kk_) << 9) + lane8];

#define DO_MFMA(MH, NH)                                                           \
  __builtin_amdgcn_s_setprio(1);                                                  \
  _Pragma("unroll") for (int m_ = 0; m_ < 4; ++m_)                                \
  _Pragma("unroll") for (int n_ = 0; n_ < 2; ++n_)                                \
  _Pragma("unroll") for (int kk_ = 0; kk_ < 2; ++kk_)                             \
    acc[(MH)*4 + m_][(NH)*2 + n_] = __builtin_amdgcn_mfma_f32_16x16x32_bf16(      \
        af[m_][kk_], bfr[(NH)*2 + n_][kk_], acc[(MH)*4 + m_][(NH)*2 + n_], 0, 0, 0); \
  __builtin_amdgcn_s_setprio(0);

__global__ __launch_bounds__(512, 1) void gates256_kernel(
    const ushort_t* __restrict__ A, const ushort_t* __restrict__ B,
    const float* __restrict__ bias, float* __restrict__ cbuf,
    ushort_t* __restrict__ hout) {
  __shared__ __align__(16) ushort_t ldsA[2][16384];
  __shared__ __align__(16) ushort_t ldsB[2][16384];
  const int tid = threadIdx.x;
  const int lane = tid & 63;
  const int wave = tid >> 6;
  const int wmi = wave >> 2;   // 0..1 -> 128 rows
  const int wni = wave & 3;    // 0..3 -> 64 cols
  const int wmi8 = wmi * 8, wni4 = wni * 4, lane8 = lane * 8;

  // XCD-aware bijective swizzle over 256 blocks (cpx = 32)
  const int bid = blockIdx.y * 16 + blockIdx.x;
  const int swz = (bid & 7) * 32 + (bid >> 3);
  const int bm = (swz & 15) * 256;
  const int bn = (swz >> 4) * 256;

  // stage base: thread tid covers fragLocal = g*8 + (tid>>6) of a half-tile
  // (rbl = fl>>1, kk = fl&1); source is frag-order (1KB lane-linear per frag),
  // dest linear in tid -> LDS frag (rb*2+kk)*512.
  const int fl0 = tid >> 6;      // 0..7
  const int srb = fl0 >> 1;      // 0..3
  const int skk = fl0 & 1;
  const ushort_t* gA0 = A + (((size_t)((bm >> 4) + srb) * 48 + skk) << 9) + ((tid & 63) << 3);
  const ushort_t* gB0 = B + (((size_t)((bn >> 4) + srb) * 48 + skk) << 9) + ((tid & 63) << 3);

  auto STAGE_A = [&](int buf, int tt, int h) {
    const size_t o = (((size_t)h * 384) + (size_t)tt * 2) << 9;  // h*8*48 + tt*2 frags
    gload16(gA0 + o, &ldsA[buf][h * 8192 + tid * 8]);
    gload16(gA0 + o + ((size_t)192 << 9), &ldsA[buf][h * 8192 + 4096 + tid * 8]);  // +4*48 frags
  };
  auto STAGE_B = [&](int buf, int tt, int h) {
    const size_t o = (((size_t)h * 384) + (size_t)tt * 2) << 9;
    gload16(gB0 + o, &ldsB[buf][h * 8192 + tid * 8]);
    gload16(gB0 + o + ((size_t)192 << 9), &ldsB[buf][h * 8192 + 4096 + tid * 8]);
  };

  f32x4 acc[8][4] = {};
  bf16x8 af[4][2];
  bf16x8 bfr[4][2];

  // prologue: tiles 0 (buf0) and 1 (buf1) fully staged; vmcnt(8) -> tile0 landed
  STAGE_A(0, 0, 0); STAGE_A(0, 0, 1); STAGE_B(0, 0, 0); STAGE_B(0, 0, 1);
  STAGE_A(1, 1, 0); STAGE_A(1, 1, 1); STAGE_B(1, 1, 0); STAGE_B(1, 1, 1);
  asm volatile("s_waitcnt vmcnt(8)" ::: "memory");
  __builtin_amdgcn_sched_barrier(0);
  __builtin_amdgcn_s_barrier();

  for (int i = 0; i < 12; ++i) {  // 2 K-tiles per iteration, K = 24*64
    const bool stg = (i <= 10);
    // ---- P1 (tile 2i, quadrant m0-3 x n0-1)
    RD_A(ldsA[0], 0); RD_B(ldsB[0], 0);
    if (i >= 1) STAGE_A(1, 2 * i + 1, 0);
    __builtin_amdgcn_s_barrier();
    DO_MFMA(0, 0);
    __builtin_amdgcn_s_barrier();
    // ---- P2 (m0-3 x n2-3)
    RD_B(ldsB[0], 1);
    if (i >= 1) STAGE_A(1, 2 * i + 1, 1);
    __builtin_amdgcn_s_barrier();
    DO_MFMA(0, 1);
    __builtin_amdgcn_s_barrier();
    // ---- P3 (m4-7 x n0-1)
    RD_A(ldsA[0], 1);
    if (stg) STAGE_B(0, 2 * i + 2, 0);
    __builtin_amdgcn_s_barrier();
    DO_MFMA(1, 0);
    __builtin_amdgcn_s_barrier();
    // ---- P4 (m4-7 x n2-3) + vmcnt
    if (stg) STAGE_B(0, 2 * i + 2, 1);
    __builtin_amdgcn_s_barrier();
    DO_MFMA(1, 1);
    if (i < 11) asm volatile("s_waitcnt vmcnt(4)" ::: "memory");
    else        asm volatile("s_waitcnt vmcnt(0)" ::: "memory");
    __builtin_amdgcn_sched_barrier(0);
    __builtin_amdgcn_s_barrier();
    // ---- P5 (tile 2i+1, m0-3 x n0-1)
    RD_A(ldsA[1], 0); RD_B(ldsB[1], 0);
    if (stg) STAGE_A(0, 2 * i + 2, 0);
    __builtin_amdgcn_s_barrier();
    DO_MFMA(0, 0);
    __builtin_amdgcn_s_barrier();
    // ---- P6 (m0-3 x n2-3)
    RD_B(ldsB[1], 1);
    if (stg) STAGE_A(0, 2 * i + 2, 1);
    __builtin_amdgcn_s_barrier();
    DO_MFMA(0, 1);
    __builtin_amdgcn_s_barrier();
    // ---- P7 (m4-7 x n0-1)
    RD_A(ldsA[1], 1);
    if (stg) STAGE_B(1, 2 * i + 3, 0);
    __builtin_amdgcn_s_barrier();
    DO_MFMA(1, 0);
    __builtin_amdgcn_s_barrier();
    // ---- P8 (m4-7 x n2-3) + vmcnt
    if (stg) STAGE_B(1, 2 * i + 3, 1);
    __builtin_amdgcn_s_barrier();
    DO_MFMA(1, 1);
    if (i < 11) {
      asm volatile("s_waitcnt vmcnt(4)" ::: "memory");
      __builtin_amdgcn_sched_barrier(0);
    }
    __builtin_amdgcn_s_barrier();
  }

  // fused LSTM epilogue: 64-col group = gates i,f,g,o for 16 hidden units
  const int colbase = bn + wni * 64;
  const int jj = (colbase >> 6) * 16 + (lane & 15);
  const int cb = colbase + (lane & 15);
  const float bI = bias[cb];
  const float bF = bias[cb + 16];
  const float bG = bias[cb + 32];
  const float bO = bias[cb + 48];
  const size_t kpart = (size_t)(16 + (jj >> 5)) * 512 + ((jj & 31) >> 3) * 128 + (jj & 7);
  const int q4 = (lane >> 4) << 2;
#pragma unroll
  for (int m = 0; m < 8; ++m) {
    const size_t rowbase = (size_t)((bm >> 4) + wmi * 8 + m) * 24576 + kpart;
#pragma unroll
    for (int r = 0; r < 4; ++r) {
      const int b = bm + wmi * 128 + m * 16 + q4 + r;
      float ig = sigf(acc[m][0][r] + bI);
      float fg = sigf(acc[m][1][r] + bF);
      float gg = tanhfast(acc[m][2][r] + bG);
      float og = sigf(acc[m][3][r] + bO);
      size_t cidx = (size_t)b * HID + jj;
      float cn = fg * cbuf[cidx] + ig * gg;
      cbuf[cidx] = cn;
      hout[rowbase + (q4 + r) * 8] = f2bf(og * tanhfast(cn));
    }
  }
}

// ---------------------------------------------------------------------------
// fcin GEMM: UNCHANGED from R7 (64x128, dbuf, counted vmcnt, fused fcout).
// ---------------------------------------------------------------------------
__global__ void fcin64_kernel(const ushort_t* __restrict__ Xf,
                              const ushort_t* __restrict__ B,
                              const float* __restrict__ bias, ushort_t* __restrict__ hout,
                              const float* __restrict__ Wout, const float* __restrict__ bout,
                              float* __restrict__ outp, int t) {
  __shared__ __align__(16) ushort_t ldsA[2][4 * 512];
  __shared__ __align__(16) ushort_t ldsB[2][8 * 512];
  __shared__ float ldsW[2048];
  const int tid = threadIdx.x;
  const int lane = tid & 63;
  const int wave = tid >> 6;
  const int wmi = wave >> 1;
  const int wni = wave & 1;

  int bid = blockIdx.y * gridDim.x + blockIdx.x;  // nwg = 256, %8==0
  int nwg = gridDim.x * gridDim.y;
  int cpx = nwg >> 3;
  int swz = (bid & 7) * cpx + (bid >> 3);
  int bx = swz % gridDim.x;
  int by = swz / gridDim.x;
  const int bm = bx * 64;
  const int bn = by * 128;
  const bool doOut = (by == 0);

  {
    float4 w0 = *(const float4*)(Wout + tid * 8);
    float4 w1 = *(const float4*)(Wout + tid * 8 + 4);
    *(float4*)(ldsW + tid * 8) = w0;
    *(float4*)(ldsW + tid * 8 + 4) = w1;
  }

  f32x4 acc[2][4] = {};
  float lo0 = 0.f, lo1 = 0.f;
  const int orow = tid >> 2, okq = tid & 3;
  const int ofr = orow >> 4, orw = orow & 15;

  const ushort_t* gA = Xf + ((size_t)((bm >> 4) + wave) * 48 + 16) * 512 + lane * 8;
  const ushort_t* gB0 = B + ((size_t)((bn >> 4) + 2 * wave) * 32) * 512 + lane * 8;
  const ushort_t* gB1 = B + ((size_t)((bn >> 4) + 2 * wave + 1) * 32) * 512 + lane * 8;

  gload16(gA, &ldsA[0][wave * 512]);
  gload16(gB0, &ldsB[0][(2 * wave) * 512]);
  gload16(gB1, &ldsB[0][(2 * wave + 1) * 512]);
  gload16(gA + 512, &ldsA[1][wave * 512]);
  gload16(gB0 + 512, &ldsB[1][(2 * wave) * 512]);
  gload16(gB1 + 512, &ldsB[1][(2 * wave + 1) * 512]);
  asm volatile("s_waitcnt vmcnt(3) lgkmcnt(0)" ::: "memory");
  __builtin_amdgcn_sched_barrier(0);
  __builtin_amdgcn_s_barrier();

  for (int kk = 0; kk < 32; ++kk) {
    const int cur = kk & 1;
    const ushort_t* lA = ldsA[cur];
    const ushort_t* lB = ldsB[cur];

    bf16x8 af[2], bf[4];
#pragma unroll
    for (int m = 0; m < 2; ++m)
      af[m] = *(const bf16x8*)(lA + (wmi * 2 + m) * 512 + lane * 8);
#pragma unroll
    for (int n = 0; n < 4; ++n)
      bf[n] = *(const bf16x8*)(lB + (wni * 4 + n) * 512 + lane * 8);

    if (doOut) {
      u16x8 h = *(const u16x8*)(lA + ofr * 512 + (okq * 16 + orw) * 8);
      const float* w0 = ldsW + kk * 32 + okq * 8;
      const float* w1 = ldsW + 1024 + kk * 32 + okq * 8;
#pragma unroll
      for (int e = 0; e < 8; ++e) {
        float hv = bf2f(h[e]);
        lo0 += hv * w0[e];
        lo1 += hv * w1[e];
      }
    }

    asm volatile("s_waitcnt lgkmcnt(0)" ::: "memory");
    __builtin_amdgcn_sched_barrier(0);
    __builtin_amdgcn_s_barrier();

    if (kk + 2 < 32) {
      const int ko = (kk + 2) * 512;
      gload16(gA + ko, &ldsA[cur][wave * 512]);
      gload16(gB0 + ko, &ldsB[cur][(2 * wave) * 512]);
      gload16(gB1 + ko, &ldsB[cur][(2 * wave + 1) * 512]);
    }

    __builtin_amdgcn_s_setprio(1);
#pragma unroll
    for (int m = 0; m < 2; ++m)
#pragma unroll
      for (int n = 0; n < 4; ++n)
        acc[m][n] = __builtin_amdgcn_mfma_f32_16x16x32_bf16(af[m], bf[n], acc[m][n], 0, 0, 0);
    __builtin_amdgcn_s_setprio(0);

    if (kk + 2 < 32) {
      asm volatile("s_waitcnt vmcnt(3)" ::: "memory");
    } else if (kk == 30) {
      asm volatile("s_waitcnt vmcnt(0)" ::: "memory");
    }
    __builtin_amdgcn_sched_barrier(0);
    if (kk < 31) __builtin_amdgcn_s_barrier();
  }

  const int q4 = (lane >> 4) << 2;
#pragma unroll
  for (int mi = 0; mi < 2; ++mi) {
    const size_t rowbase = (size_t)((bm >> 4) + wmi * 2 + mi) * 24576;
#pragma unroll
    for (int ni = 0; ni < 4; ++ni) {
      const int n = bn + wni * 64 + ni * 16 + (lane & 15);
      const float bb = bias[n];
      const size_t kpart = (size_t)(n >> 5) * 512 + ((n & 31) >> 3) * 128 + (n & 7);
#pragma unroll
      for (int r = 0; r < 4; ++r) {
        float v = fmaxf(acc[mi][ni][r] + bb, 0.f);
        hout[rowbase + kpart + (q4 + r) * 8] = f2bf(v);
      }
    }
  }

  if (doOut) {
    lo0 += __shfl_xor(lo0, 1);
    lo1 += __shfl_xor(lo1, 1);
    lo0 += __shfl_xor(lo0, 2);
    lo1 += __shfl_xor(lo1, 2);
    if (okq == 0) {
      float l0 = lo0 + bout[0];
      float l1 = lo1 + bout[1];
      float m = fmaxf(l0, l1);
      float e0 = __expf(l0 - m), e1 = __expf(l1 - m);
      float inv = 1.f / (e0 + e1);
      float* o = outp + (size_t)(bm + orow) * (NDAYS * NOUT) + t * NOUT;
      o[0] = e0 * inv;
      o[1] = e1 * inv;
    }
  }
}

extern "C" void kernel_launch(void* const* d_in, const int* in_sizes, int n_in, void* d_out,
                              int out_size, void* d_ws, size_t ws_size, hipStream_t stream) {
  const float* hx = (const float*)d_in[0];
  const float* cx = (const float*)d_in[1];
  const float* Wih = (const float*)d_in[2];
  const float* Whh = (const float*)d_in[3];
  const float* bih = (const float*)d_in[4];
  const float* bhh = (const float*)d_in[5];
  const float* Wfcin = (const float*)d_in[6];
  const float* bfcin = (const float*)d_in[7];
  const float* Wfcout = (const float*)d_in[8];
  const float* bfcout = (const float*)d_in[9];
  const float* Wspan = (const float*)d_in[10];
  const float* bspan = (const float*)d_in[11];
  float* out = (float*)d_out;

  char* ws = (char*)d_ws;
  ushort_t* Wgf = (ushort_t*)(ws);               // 4096*1536*2 = 12582912
  ushort_t* Wfcf = (ushort_t*)(ws + 12582912);   // 512*1024*2  =  1048576
  float* bg = (float*)(ws + 13631488);           // 4096*4      =    16384
  ushort_t* XA = (ushort_t*)(ws + 13647872);     // 12582912
  ushort_t* XB = (ushort_t*)(ws + 26230784);     // 12582912
  float* cbuf = (float*)(ws + 38813696);         // 16777216 -> total 55590912 B

  prep_gates_w<<<3072, 256, 0, stream>>>(Wih, Whh, bih, bhh, Wgf, bg);
  prep_fcin_w<<<256, 256, 0, stream>>>(Wfcin, Wfcf);
  init_x<<<3072, 256, 0, stream>>>(hx, XA);
  hipMemcpyAsync(cbuf, cx, (size_t)BSZ * HID * 4, hipMemcpyDeviceToDevice, stream);
  span_kernel<<<(BSZ * NSPAN) / 256, 256, 0, stream>>>(hx, Wspan, bspan, out);

  float* outp = out + BSZ * NSPAN;
  for (int t = 0; t < NDAYS; ++t) {
    ushort_t* Xin = (t & 1) ? XB : XA;
    ushort_t* Xout = (t & 1) ? XA : XB;
    gates256_kernel<<<dim3(16, 16), 512, 0, stream>>>(Xin, Wgf, bg, cbuf, Xout);
    if (t < NDAYS - 1) {
      fcin64_kernel<<<dim3(64, 4), 256, 0, stream>>>(Xout, Wfcf, bfcin, Xout,
                                                     Wfcout, bfcout, outp, t);
    } else {
      fcout_kernel<<<BSZ / 4, 256, 0, stream>>>(Xout, Wfcout, bfcout, outp, t);
    }
  }
}

// Round 9
// 1518.033 us; speedup vs baseline: 2.4009x; 1.0144x over previous
//
#include <hip/hip_runtime.h>

typedef __bf16 bf16x8 __attribute__((ext_vector_type(8)));
typedef float f32x4 __attribute__((ext_vector_type(4)));
typedef unsigned short ushort_t;
typedef unsigned short u16x8 __attribute__((ext_vector_type(8)));

#define BSZ 4096
#define HID 1024
#define INPD 512
#define NSPAN 8
#define NOUT 2
#define NDAYS 20
#define XLD 1536  // X = [inp(512) | h(1024)] K-dim

// Frag-order layout: element (row, k) of a [R][K] bf16 matrix lives at
//   ((row>>4)*(K/32) + (k>>5))*512 + ((k&31)>>3)*128 + (row&15)*8 + (k&7)
// each 16x32 MFMA fragment is 1KB contiguous = exact mfma_16x16x32 operand map.

__device__ __forceinline__ ushort_t f2bf(float f) {
  union { float f; unsigned u; } v; v.f = f;
  unsigned r = v.u + 0x7FFFu + ((v.u >> 16) & 1u);
  return (ushort_t)(r >> 16);
}
__device__ __forceinline__ float bf2f(ushort_t b) {
  union { unsigned u; float f; } v; v.u = ((unsigned)b) << 16;
  return v.f;
}
__device__ __forceinline__ float sigf(float x) { return 1.f / (1.f + __expf(-x)); }
__device__ __forceinline__ float tanhfast(float x) { return 2.f / (1.f + __expf(-2.f * x)) - 1.f; }

__device__ __forceinline__ void gload16(const void* g, void* l) {
  __builtin_amdgcn_global_load_lds((const __attribute__((address_space(1))) void*)g,
                                   (__attribute__((address_space(3))) void*)l, 16, 0, 0);
}

// ---------------------------------------------------------------------------
// Wg prep -> frag-order. Gate-reordered row r_perm = (j/16)*64 + gate*16 + (j%16).
// ---------------------------------------------------------------------------
__global__ void prep_gates_w(const float* __restrict__ Wih, const float* __restrict__ Whh,
                             const float* __restrict__ bih, const float* __restrict__ bhh,
                             ushort_t* __restrict__ Wgf, float* __restrict__ bg) {
  int gid = blockIdx.x * 256 + threadIdx.x;
  int rb = gid / 3072;           // 48*64
  int rem = gid - rb * 3072;
  int kk = rem >> 6;
  int li = rem & 63;
  int rp = rb * 16 + (li & 15);
  int kb = kk * 32 + ((li >> 4) << 3);
  int g = (rp >> 4) & 3;
  int j = (rp >> 6) * 16 + (rp & 15);
  int src = g * HID + j;
  const float* s = (kb < INPD) ? (Wih + (size_t)src * INPD + kb)
                               : (Whh + (size_t)src * HID + (kb - INPD));
  u16x8 o;
#pragma unroll
  for (int e = 0; e < 8; ++e) o[e] = f2bf(s[e]);
  *(u16x8*)(Wgf + (size_t)gid * 8) = o;
  if (kk == 0 && li < 16) bg[rp] = bih[src] + bhh[src];
}

// Wfc2 prep -> frag-order [576][1024]: rows 0..511 = Wfcin, 512..513 = Wfcout,
// 514..575 = 0.  gid over 576*1024/8 = 73728 -> 288 blocks.
__global__ void prep_fcin_w(const float* __restrict__ W, const float* __restrict__ Wout,
                            ushort_t* __restrict__ Wf) {
  int gid = blockIdx.x * 256 + threadIdx.x;
  int rb = gid / 2048;           // 32*64
  int rem = gid - rb * 2048;
  int kk = rem >> 6;
  int li = rem & 63;
  int row = rb * 16 + (li & 15);
  int kb = kk * 32 + ((li >> 4) << 3);
  u16x8 o;
  if (row < 512) {
    const float* s = W + (size_t)row * HID + kb;
#pragma unroll
    for (int e = 0; e < 8; ++e) o[e] = f2bf(s[e]);
  } else if (row < 514) {
    const float* s = Wout + (size_t)(row - 512) * HID + kb;
#pragma unroll
    for (int e = 0; e < 8; ++e) o[e] = f2bf(s[e]);
  } else {
#pragma unroll
    for (int e = 0; e < 8; ++e) o[e] = 0;
  }
  *(u16x8*)(Wf + (size_t)gid * 8) = o;
}

// X init (frag-order): inp part zeros, h part = bf16(hx)
__global__ void init_x(const float* __restrict__ hx, ushort_t* __restrict__ Xf) {
  int gid = blockIdx.x * 256 + threadIdx.x;
  int rb = gid / 3072;
  int rem = gid - rb * 3072;
  int kk = rem >> 6;
  int li = rem & 63;
  int row = rb * 16 + (li & 15);
  int kb = kk * 32 + ((li >> 4) << 3);
  u16x8 o;
  if (kb < INPD) {
#pragma unroll
    for (int e = 0; e < 8; ++e) o[e] = 0;
  } else {
    const float* s = hx + (size_t)row * HID + (kb - INPD);
#pragma unroll
    for (int e = 0; e < 8; ++e) o[e] = f2bf(s[e]);
  }
  *(u16x8*)(Xf + (size_t)gid * 8) = o;
}

// num_spans = softmax(hx @ W_span.T + b_span), fp32
__global__ void span_kernel(const float* __restrict__ hx, const float* __restrict__ Wspan,
                            const float* __restrict__ bspan, float* __restrict__ out) {
  int gid = blockIdx.x * 256 + threadIdx.x;  // over 4096*8
  int b = gid >> 3, o = gid & 7;
  const float4* hr = (const float4*)(hx + (size_t)b * HID);
  const float4* wr = (const float4*)(Wspan + (size_t)o * HID);
  float acc = 0.f;
  for (int i = 0; i < HID / 4; ++i) {
    float4 h = hr[i], w = wr[i];
    acc += h.x * w.x + h.y * w.y + h.z * w.z + h.w * w.w;
  }
  acc += bspan[o];
  float m = acc;
  for (int s = 1; s < 8; s <<= 1) m = fmaxf(m, __shfl_xor(m, s));
  float e = __expf(acc - m);
  float ssum = e;
  for (int s = 1; s < 8; s <<= 1) ssum += __shfl_xor(ssum, s);
  out[gid] = e / ssum;
}

// standalone fcout (only t = NDAYS-1), reads frag-order X
__global__ void fcout_kernel(const ushort_t* __restrict__ Xf, const float* __restrict__ W,
                             const float* __restrict__ bvec, float* __restrict__ outp, int t) {
  const int lane = threadIdx.x & 63;
  const int wave = threadIdx.x >> 6;
  const int b = blockIdx.x * 4 + wave;
  const int rb = b >> 4, r = b & 15;
  const int kk = 16 + (lane >> 1);
  const int ss = (lane & 1) * 2;
  const size_t base = ((size_t)rb * 48 + kk) * 512 + (ss * 16 + r) * 8;
  u16x8 h0 = *(const u16x8*)(Xf + base);
  u16x8 h1 = *(const u16x8*)(Xf + base + 128);
  const float* w0 = W + lane * 16;
  const float* w1 = W + HID + lane * 16;
  float l0 = 0.f, l1 = 0.f;
#pragma unroll
  for (int j = 0; j < 8; ++j) {
    float ha = bf2f(h0[j]);
    l0 += ha * w0[j];
    l1 += ha * w1[j];
    float hb = bf2f(h1[j]);
    l0 += hb * w0[j + 8];
    l1 += hb * w1[j + 8];
  }
#pragma unroll
  for (int s = 32; s > 0; s >>= 1) {
    l0 += __shfl_xor(l0, s);
    l1 += __shfl_xor(l1, s);
  }
  if (lane == 0) {
    l0 += bvec[0];
    l1 += bvec[1];
    float m = fmaxf(l0, l1);
    float e0 = __expf(l0 - m), e1 = __expf(l1 - m);
    float inv = 1.f / (e0 + e1);
    float* o = outp + (size_t)b * (NDAYS * NOUT) + t * NOUT;
    o[0] = e0 * inv;
    o[1] = e1 * inv;
  }
}

// ---------------------------------------------------------------------------
// Gates GEMM: 128x128 / BK=32 / 4-wave, frag-order operands, frag-linear LDS.
// EXACT R7 version (59.5 us = 866 TF, m97-structure ceiling).
// ---------------------------------------------------------------------------
__global__ void gates128_kernel(const ushort_t* __restrict__ A,
                                const ushort_t* __restrict__ B,
                                const float* __restrict__ bias, float* __restrict__ cbuf,
                                ushort_t* __restrict__ hout) {
  __shared__ __align__(16) ushort_t ldsA[8 * 512];
  __shared__ __align__(16) ushort_t ldsB[8 * 512];
  const int tid = threadIdx.x;
  const int lane = tid & 63;
  const int wave = tid >> 6;

  int bid = blockIdx.y * gridDim.x + blockIdx.x;
  int nwg = gridDim.x * gridDim.y;
  int cpx = nwg >> 3;
  int swz = (bid & 7) * cpx + (bid >> 3);
  int bx = swz % gridDim.x;
  int by = swz / gridDim.x;
  const int bm = bx * 128;
  const int bn = by * 128;
  const int wm = (wave >> 1) * 64;
  const int wn = (wave & 1) * 64;

  f32x4 acc[4][4] = {};

  const int f0 = wave * 2, f1 = wave * 2 + 1;
  const ushort_t* gA0 = A + ((size_t)((bm >> 4) + f0) * 48) * 512 + lane * 8;
  const ushort_t* gA1 = A + ((size_t)((bm >> 4) + f1) * 48) * 512 + lane * 8;
  const ushort_t* gB0 = B + ((size_t)((bn >> 4) + f0) * 48) * 512 + lane * 8;
  const ushort_t* gB1 = B + ((size_t)((bn >> 4) + f1) * 48) * 512 + lane * 8;

  for (int kk = 0; kk < 48; ++kk) {
    const int ko = kk * 512;
    gload16(gA0 + ko, ldsA + f0 * 512);
    gload16(gA1 + ko, ldsA + f1 * 512);
    gload16(gB0 + ko, ldsB + f0 * 512);
    gload16(gB1 + ko, ldsB + f1 * 512);
    __syncthreads();

    bf16x8 af[4], bf[4];
#pragma unroll
    for (int i = 0; i < 4; ++i) {
      af[i] = *(const bf16x8*)(ldsA + ((wm >> 4) + i) * 512 + lane * 8);
      bf[i] = *(const bf16x8*)(ldsB + ((wn >> 4) + i) * 512 + lane * 8);
    }
#pragma unroll
    for (int mi = 0; mi < 4; ++mi)
#pragma unroll
      for (int ni = 0; ni < 4; ++ni)
        acc[mi][ni] = __builtin_amdgcn_mfma_f32_16x16x32_bf16(af[mi], bf[ni], acc[mi][ni], 0, 0, 0);
    __syncthreads();
  }

  const int colbase = bn + wn;
  const int jj = (colbase >> 6) * 16 + (lane & 15);
  const int cb = colbase + (lane & 15);
  const float bI = bias[cb];
  const float bF = bias[cb + 16];
  const float bG = bias[cb + 32];
  const float bO = bias[cb + 48];
  const size_t kpart = (size_t)(16 + (jj >> 5)) * 512 + ((jj & 31) >> 3) * 128 + (jj & 7);
  const int q4 = (lane >> 4) << 2;
#pragma unroll
  for (int mi = 0; mi < 4; ++mi) {
    const size_t rowbase = (size_t)(((bm + wm) >> 4) + mi) * 24576 + kpart;
#pragma unroll
    for (int r = 0; r < 4; ++r) {
      const int b = bm + wm + mi * 16 + q4 + r;
      float ig = sigf(acc[mi][0][r] + bI);
      float fg = sigf(acc[mi][1][r] + bF);
      float gg = tanhfast(acc[mi][2][r] + bG);
      float og = sigf(acc[mi][3][r] + bO);
      size_t cidx = (size_t)b * HID + jj;
      float cn = fg * cbuf[cidx] + ig * gg;
      cbuf[cidx] = cn;
      hout[rowbase + (q4 + r) * 8] = f2bf(og * tanhfast(cn));
    }
  }
}

// ---------------------------------------------------------------------------
// fcin DIRECT-REGISTER GEMM (all operands L2-resident; no LDS, no barriers).
// 1152 independent 32x64 wave-tiles: m_idx 0..127 (32 rows), n_idx 0..8.
// n_idx<8: relu(h @ Wfc^T + b) -> inp part of X (frag-order).
// n_idx==8: B rows 512/513 = Wfcout -> logits in cols 0/1; softmax -> outp.
// 288 blocks x 4 waves; 6 coalesced dwordx4 loads/iter, 1-iter prefetch.
// ---------------------------------------------------------------------------
__global__ __launch_bounds__(256) void fcin_direct(
    const ushort_t* __restrict__ Xf, const ushort_t* __restrict__ Bw,
    const float* __restrict__ bias, ushort_t* __restrict__ hout,
    const float* __restrict__ bout, float* __restrict__ outp, int t) {
  const int tid = threadIdx.x;
  const int lane = tid & 63;
  const int wave = tid >> 6;
  const int bid = blockIdx.x;                    // 288, %8==0
  const int swz = (bid & 7) * 36 + (bid >> 3);   // bijective XCD swizzle
  const int wt = swz * 4 + wave;                 // 0..1151
  const int n_idx = wt >> 7;                     // 0..8
  const int m_idx = wt & 127;

  const ushort_t* pA0 = Xf + (((size_t)(m_idx * 2 + 0) * 48 + 16) << 9) + lane * 8;
  const ushort_t* pA1 = Xf + (((size_t)(m_idx * 2 + 1) * 48 + 16) << 9) + lane * 8;
  const ushort_t* pB0 = Bw + (((size_t)(n_idx * 4 + 0) * 32) << 9) + lane * 8;
  const ushort_t* pB1 = Bw + (((size_t)(n_idx * 4 + 1) * 32) << 9) + lane * 8;
  const ushort_t* pB2 = Bw + (((size_t)(n_idx * 4 + 2) * 32) << 9) + lane * 8;
  const ushort_t* pB3 = Bw + (((size_t)(n_idx * 4 + 3) * 32) << 9) + lane * 8;

  f32x4 acc[2][4] = {};
  bf16x8 aC0, aC1, bC[4], aN0, aN1, bN[4];

  aC0 = *(const bf16x8*)(pA0);
  aC1 = *(const bf16x8*)(pA1);
  bC[0] = *(const bf16x8*)(pB0);
  bC[1] = *(const bf16x8*)(pB1);
  bC[2] = *(const bf16x8*)(pB2);
  bC[3] = *(const bf16x8*)(pB3);

#pragma unroll 2
  for (int kp = 0; kp < 16; ++kp) {
    const int o1 = (2 * kp + 1) << 9;
    aN0 = *(const bf16x8*)(pA0 + o1);
    aN1 = *(const bf16x8*)(pA1 + o1);
    bN[0] = *(const bf16x8*)(pB0 + o1);
    bN[1] = *(const bf16x8*)(pB1 + o1);
    bN[2] = *(const bf16x8*)(pB2 + o1);
    bN[3] = *(const bf16x8*)(pB3 + o1);
#pragma unroll
    for (int ni = 0; ni < 4; ++ni) {
      acc[0][ni] = __builtin_amdgcn_mfma_f32_16x16x32_bf16(aC0, bC[ni], acc[0][ni], 0, 0, 0);
      acc[1][ni] = __builtin_amdgcn_mfma_f32_16x16x32_bf16(aC1, bC[ni], acc[1][ni], 0, 0, 0);
    }
    if (kp < 15) {
      const int o2 = (2 * kp + 2) << 9;
      aC0 = *(const bf16x8*)(pA0 + o2);
      aC1 = *(const bf16x8*)(pA1 + o2);
      bC[0] = *(const bf16x8*)(pB0 + o2);
      bC[1] = *(const bf16x8*)(pB1 + o2);
      bC[2] = *(const bf16x8*)(pB2 + o2);
      bC[3] = *(const bf16x8*)(pB3 + o2);
    }
#pragma unroll
    for (int ni = 0; ni < 4; ++ni) {
      acc[0][ni] = __builtin_amdgcn_mfma_f32_16x16x32_bf16(aN0, bN[ni], acc[0][ni], 0, 0, 0);
      acc[1][ni] = __builtin_amdgcn_mfma_f32_16x16x32_bf16(aN1, bN[ni], acc[1][ni], 0, 0, 0);
    }
  }

  const int q4 = (lane >> 4) << 2;
  if (n_idx < 8) {
#pragma unroll
    for (int mi = 0; mi < 2; ++mi) {
      const size_t rowbase = (size_t)(m_idx * 2 + mi) * 24576;
#pragma unroll
      for (int ni = 0; ni < 4; ++ni) {
        const int n = n_idx * 64 + ni * 16 + (lane & 15);
        const float bb = bias[n];
        const size_t kpart = (size_t)(n >> 5) * 512 + ((n & 31) >> 3) * 128 + (n & 7);
#pragma unroll
        for (int r = 0; r < 4; ++r) {
          float v = fmaxf(acc[mi][ni][r] + bb, 0.f);
          hout[rowbase + kpart + (q4 + r) * 8] = f2bf(v);
        }
      }
    }
  } else {
    const float b0 = bout[0], b1 = bout[1];
#pragma unroll
    for (int mi = 0; mi < 2; ++mi) {
#pragma unroll
      for (int r = 0; r < 4; ++r) {
        float raw = acc[mi][0][r];
        float partner = __shfl_xor(raw, 1);
        if ((lane & 15) == 0) {
          float l0 = raw + b0;
          float l1 = partner + b1;
          float m = fmaxf(l0, l1);
          float e0 = __expf(l0 - m), e1 = __expf(l1 - m);
          float inv = 1.f / (e0 + e1);
          const int row = m_idx * 32 + mi * 16 + q4 + r;
          float* o = outp + (size_t)row * (NDAYS * NOUT) + t * NOUT;
          o[0] = e0 * inv;
          o[1] = e1 * inv;
        }
      }
    }
  }
}

extern "C" void kernel_launch(void* const* d_in, const int* in_sizes, int n_in, void* d_out,
                              int out_size, void* d_ws, size_t ws_size, hipStream_t stream) {
  const float* hx = (const float*)d_in[0];
  const float* cx = (const float*)d_in[1];
  const float* Wih = (const float*)d_in[2];
  const float* Whh = (const float*)d_in[3];
  const float* bih = (const float*)d_in[4];
  const float* bhh = (const float*)d_in[5];
  const float* Wfcin = (const float*)d_in[6];
  const float* bfcin = (const float*)d_in[7];
  const float* Wfcout = (const float*)d_in[8];
  const float* bfcout = (const float*)d_in[9];
  const float* Wspan = (const float*)d_in[10];
  const float* bspan = (const float*)d_in[11];
  float* out = (float*)d_out;

  char* ws = (char*)d_ws;
  ushort_t* Wgf = (ushort_t*)(ws);               // 4096*1536*2 = 12582912
  ushort_t* Wfc2 = (ushort_t*)(ws + 12582912);   // 576*1024*2  =  1179648
  float* bg = (float*)(ws + 13762560);           // 4096*4      =    16384
  ushort_t* XA = (ushort_t*)(ws + 13778944);     // 12582912
  ushort_t* XB = (ushort_t*)(ws + 26361856);     // 12582912
  float* cbuf = (float*)(ws + 38944768);         // 16777216 -> total 55721984 B

  prep_gates_w<<<3072, 256, 0, stream>>>(Wih, Whh, bih, bhh, Wgf, bg);
  prep_fcin_w<<<288, 256, 0, stream>>>(Wfcin, Wfcout, Wfc2);
  init_x<<<3072, 256, 0, stream>>>(hx, XA);
  hipMemcpyAsync(cbuf, cx, (size_t)BSZ * HID * 4, hipMemcpyDeviceToDevice, stream);
  span_kernel<<<(BSZ * NSPAN) / 256, 256, 0, stream>>>(hx, Wspan, bspan, out);

  float* outp = out + BSZ * NSPAN;
  for (int t = 0; t < NDAYS; ++t) {
    ushort_t* Xin = (t & 1) ? XB : XA;
    ushort_t* Xout = (t & 1) ? XA : XB;
    gates128_kernel<<<dim3(32, 32), 256, 0, stream>>>(Xin, Wgf, bg, cbuf, Xout);
    if (t < NDAYS - 1) {
      fcin_direct<<<288, 256, 0, stream>>>(Xout, Wfc2, bfcin, Xout, bfcout, outp, t);
    } else {
      fcout_kernel<<<BSZ / 4, 256, 0, stream>>>(Xout, Wfcout, bfcout, outp, t);
    }
  }
}